// Round 8
// baseline (412.732 us; speedup 1.0000x reference)
//
#include <hip/hip_runtime.h>
#include <hip/hip_bf16.h>
#include <stdint.h>

#define DIM 180
#define WS 16
#define OWS 24
#define HEADS 6
#define HD 30
#define MLP_HID 360
#define HH 256
#define WW 256
#define L (HH * WW)
#define NWIN 256
#define NQ 256
#define NK 576

#define KP1 192
#define KP2 384
#define NQKV 576

// 30^-0.5 * log2(e): attn logits computed in log2 domain -> raw v_exp_f32
#define QSCALE 0.2633988734672831f
#define LOG2E 1.4426950408889634f

typedef float f4v __attribute__((ext_vector_type(4)));
typedef short s8v __attribute__((ext_vector_type(8)));
typedef short s4v __attribute__((ext_vector_type(4)));

static __device__ __forceinline__ short f2bf(float x) {
    union { __hip_bfloat16 h; short s; } u;
    u.h = __float2bfloat16(x);
    return u.s;
}
static __device__ __forceinline__ uint32_t pack_bf2(float lo, float hi) {
    union { __hip_bfloat162 h; uint32_t u; } u;
    u.h.x = __float2bfloat16(lo);
    u.h.y = __float2bfloat16(hi);
    return u.u;
}
static __device__ __forceinline__ float bflo(uint32_t u) {
    union { uint32_t i; float f; } c; c.i = u << 16; return c.f;
}
static __device__ __forceinline__ float bfhi(uint32_t u) {
    union { uint32_t i; float f; } c; c.i = u & 0xffff0000u; return c.f;
}

typedef __attribute__((address_space(1))) const unsigned int ga_u32;
typedef __attribute__((address_space(3))) unsigned int la_u32;
static __device__ __forceinline__ void gld16(const void* g, void* l) {
    __builtin_amdgcn_global_load_lds((ga_u32*)g, (la_u32*)l, 16, 0, 0);
}

// ---------------- LayerNorm (LN1): 4 rows per 256-thread block (1 row/wave)
__global__ __launch_bounds__(256) void ln_kernel(const float* __restrict__ x,
                                                 const float* __restrict__ g,
                                                 const float* __restrict__ b,
                                                 __hip_bfloat16* __restrict__ out) {
    int row = blockIdx.x * 4 + (threadIdx.x >> 6);
    int t = threadIdx.x & 63;
    const float* xr = x + (size_t)row * DIM;
    float v0 = xr[t];
    float v1 = xr[t + 64];
    float v2 = (t < DIM - 128) ? xr[t + 128] : 0.f;
    float s = v0 + v1 + v2;
    #pragma unroll
    for (int o = 32; o > 0; o >>= 1) s += __shfl_down(s, o);
    s = __shfl(s, 0);
    float mu = s * (1.f / DIM);
    float d0 = v0 - mu, d1 = v1 - mu;
    float d2 = (t < DIM - 128) ? (v2 - mu) : 0.f;
    float vs = d0 * d0 + d1 * d1 + d2 * d2;
    #pragma unroll
    for (int o = 32; o > 0; o >>= 1) vs += __shfl_down(vs, o);
    vs = __shfl(vs, 0);
    float rstd = rsqrtf(vs * (1.f / DIM) + 1e-5f);
    __hip_bfloat16* orow = out + (size_t)row * KP1;
    orow[t]      = __float2bfloat16(g[t] * d0 * rstd + b[t]);
    orow[t + 64] = __float2bfloat16(g[t + 64] * d1 * rstd + b[t + 64]);
    if (t < DIM - 128)
        orow[t + 128] = __float2bfloat16(g[t + 128] * d2 * rstd + b[t + 128]);
    if (t < KP1 - DIM) orow[DIM + t] = __float2bfloat16(0.f);
}

// ---------------- Bias in C-fragment order, bf16, with in-chunk key permutation.
// D-row j of tile kc corresponds to actual key
//   k = (kc>>1)*32 + 8*(j>>2) + (kc&1)*4 + (j&3)
__global__ __launch_bounds__(256) void bias_kernel(const int* __restrict__ rpi,
                                                   const float* __restrict__ rpb,
                                                   ushort* __restrict__ biasC) {
    int idx = blockIdx.x * 256 + threadIdx.x;   // 6*36*256*16 = 884736
    int j = idx & 15;
    int q = (idx >> 4) & 255;
    int r = idx >> 12;
    int kc = r % 36;
    int head = r / 36;
    int k = (kc >> 1) * 32 + ((j >> 2) << 3) + ((kc & 1) << 2) + (j & 3);
    int t = rpi[q * NK + k];
    biasC[idx] = (ushort)f2bf(rpb[t * HEADS + head] * LOG2E);
}

// ---------------- Weight convert (q scaled by QSCALE which includes log2e)
__global__ __launch_bounds__(256) void wconv_kernel(
        const float* __restrict__ qw, const float* __restrict__ kvw,
        const float* __restrict__ pw, const float* __restrict__ w1,
        const float* __restrict__ w2, short* __restrict__ wt) {
    int idx = blockIdx.x * 256 + threadIdx.x;   // 0 .. 294911
    float v = 0.f;
    if (idx < 110592) {                          // qkv: [576][192]
        int n = idx / KP1, k = idx - n * KP1;
        if (k < DIM) {
            if (n < DIM) v = qw[k * DIM + n] * QSCALE;
            else if (n < 540) v = kvw[k * (2 * DIM) + (n - DIM)];
        }
    } else if (idx < 147456) {                   // proj: [192][192]
        int r = idx - 110592;
        int n = r / KP1, k = r - n * KP1;
        if (k < DIM && n < DIM) v = pw[k * DIM + n];
    } else if (idx < 221184) {                   // w1: [384][192]
        int r = idx - 147456;
        int n = r / KP1, k = r - n * KP1;
        if (k < DIM && n < MLP_HID) v = w1[k * MLP_HID + n];
    } else {                                     // w2: [192][384]
        int r = idx - 221184;
        int n = r / KP2, k = r - n * KP2;
        if (k < MLP_HID && n < DIM) v = w2[k * DIM + n];
    }
    wt[idx] = f2bf(v);
}

__global__ __launch_bounds__(256) void bconv_kernel(
        const float* __restrict__ qb, const float* __restrict__ kvb,
        const float* __restrict__ pb, const float* __restrict__ b1,
        const float* __restrict__ b2, float* __restrict__ bv) {
    int idx = blockIdx.x * 256 + threadIdx.x;
    if (idx >= 1344) return;
    float v = 0.f;
    if (idx < 576) {
        if (idx < DIM) v = qb[idx] * QSCALE;
        else if (idx < 540) v = kvb[idx - DIM];
    } else if (idx < 768) {
        int n = idx - 576; if (n < DIM) v = pb[n];
    } else if (idx < 1152) {
        int n = idx - 768; if (n < MLP_HID) v = b1[n];
    } else {
        int n = idx - 1152; if (n < DIM) v = b2[n];
    }
    bv[idx] = v;
}

// ---------------- MFMA GEMM, BK=32 (24 KB LDS -> 6 blocks/CU)
// mode 0: outb bf16 = r ; mode 1: outb bf16 = gelu_tanh(r) ; mode 3: outf f32 += r
__global__ __launch_bounds__(256) void mgemm(
        const short* __restrict__ A, const short* __restrict__ Wt,
        const float* __restrict__ bias,
        float* __restrict__ outf, short* __restrict__ outb,
        int lda, int ldo, int nK, int mode) {
    __shared__ short As[2][128 * 32];
    __shared__ short Wsm[2][64 * 32];
    int tid = threadIdx.x;
    int lane = tid & 63, wave = tid >> 6;
    int q15 = lane & 15, quad = lane >> 4;
    int n0 = blockIdx.x * 64;
    int m0 = blockIdx.y * 128;

    auto stage = [&](int buf, int k0) {
        int lr = lane >> 2, c = lane & 3;
        const short* Ab = A + (size_t)m0 * lda + k0;
        #pragma unroll
        for (int i = 0; i < 2; i++) {
            int r = i * 64 + wave * 16 + lr;
            gld16(Ab + (size_t)r * lda + ((c ^ (r & 3)) * 8),
                  &As[buf][(i * 64 + wave * 16) * 32]);
        }
        const short* Wb = Wt + (size_t)n0 * lda + k0;
        {
            int r = wave * 16 + lr;
            gld16(Wb + (size_t)r * lda + ((c ^ (r & 3)) * 8),
                  &Wsm[buf][(wave * 16) * 32]);
        }
    };

    f4v acc[2][4];
    #pragma unroll
    for (int a = 0; a < 2; a++)
        #pragma unroll
        for (int b = 0; b < 4; b++) acc[a][b] = (f4v){0.f, 0.f, 0.f, 0.f};

    stage(0, 0);
    __syncthreads();
    for (int ch = 0; ch < nK; ch++) {
        int buf = ch & 1;
        if (ch + 1 < nK) stage(buf ^ 1, (ch + 1) * 32);
        s8v af[2], wf[4];
        #pragma unroll
        for (int mt = 0; mt < 2; mt++) {
            int r = wave * 32 + mt * 16 + q15;
            af[mt] = *(const s8v*)&As[buf][r * 32 + ((quad ^ (r & 3)) * 8)];
        }
        #pragma unroll
        for (int nt = 0; nt < 4; nt++) {
            int r = nt * 16 + q15;
            wf[nt] = *(const s8v*)&Wsm[buf][r * 32 + ((quad ^ (r & 3)) * 8)];
        }
        #pragma unroll
        for (int mt = 0; mt < 2; mt++)
            #pragma unroll
            for (int nt = 0; nt < 4; nt++)
                acc[mt][nt] = __builtin_amdgcn_mfma_f32_16x16x32_bf16(
                    af[mt], wf[nt], acc[mt][nt], 0, 0, 0);
        __syncthreads();
    }

    #pragma unroll
    for (int mt = 0; mt < 2; mt++) {
        int mb = m0 + wave * 32 + mt * 16 + quad * 4;
        #pragma unroll
        for (int nt = 0; nt < 4; nt++) {
            int n = n0 + nt * 16 + q15;
            float bv = bias[n];
            f4v a = acc[mt][nt];
            #pragma unroll
            for (int r = 0; r < 4; r++) {
                int m = mb + r;
                float v = a[r] + bv;
                if (mode == 0) {
                    outb[(size_t)m * ldo + n] = f2bf(v);
                } else if (mode == 1) {
                    // tanh-approx gelu (max err ~3e-4, far under bf16 rounding):
                    // 0.5*v*(1+tanh(0.79788456*(v+0.044715*v^3)))
                    float y = 0.7978845608028654f * (v + 0.044715f * v * v * v);
                    // tanh(y) = 1 - 2/(1+exp2(y*2*log2e))
                    float e = __builtin_amdgcn_exp2f(y * 2.885390081777927f);
                    float th = 1.f - 2.f / (1.f + e);
                    outb[(size_t)m * ldo + n] = f2bf(0.5f * v * (1.f + th));
                } else {
                    if (n < DIM) outf[(size_t)m * DIM + n] += v;
                }
            }
        }
    }
}

// ---------------- proj + residual + LN2 fused. BM=64, full N=192 per block.
__global__ __launch_bounds__(256) void projln(
        const short* __restrict__ A, const short* __restrict__ Wt,
        const float* __restrict__ bias, const float* __restrict__ resid,
        const float* __restrict__ g2, const float* __restrict__ b2,
        float* __restrict__ outf, short* __restrict__ outb) {
    __shared__ short As[2][64 * 32];
    __shared__ short Wsm[2][192 * 32];
    int tid = threadIdx.x;
    int lane = tid & 63, wave = tid >> 6;
    int q15 = lane & 15, quad = lane >> 4;
    int m0 = blockIdx.x * 64;

    auto stage = [&](int buf, int k0) {
        int lr = lane >> 2, c = lane & 3;
        const short* Ab = A + (size_t)m0 * KP1 + k0;
        {
            int r = wave * 16 + lr;
            gld16(Ab + (size_t)r * KP1 + ((c ^ (r & 3)) * 8),
                  &As[buf][(wave * 16) * 32]);
        }
        #pragma unroll
        for (int i = 0; i < 3; i++) {
            int r = i * 64 + wave * 16 + lr;
            gld16(Wt + (size_t)r * KP1 + k0 + ((c ^ (r & 3)) * 8),
                  &Wsm[buf][(i * 64 + wave * 16) * 32]);
        }
    };

    f4v acc[12];
    #pragma unroll
    for (int b = 0; b < 12; b++) acc[b] = (f4v){0.f, 0.f, 0.f, 0.f};

    stage(0, 0);
    __syncthreads();
    for (int ch = 0; ch < KP1 / 32; ch++) {
        int buf = ch & 1;
        if (ch + 1 < KP1 / 32) stage(buf ^ 1, (ch + 1) * 32);
        int ra = wave * 16 + q15;
        s8v af = *(const s8v*)&As[buf][ra * 32 + ((quad ^ (ra & 3)) * 8)];
        #pragma unroll
        for (int nt = 0; nt < 12; nt++) {
            int r = nt * 16 + q15;
            s8v wf = *(const s8v*)&Wsm[buf][r * 32 + ((quad ^ (r & 3)) * 8)];
            acc[nt] = __builtin_amdgcn_mfma_f32_16x16x32_bf16(af, wf, acc[nt], 0, 0, 0);
        }
        __syncthreads();
    }

    float gv[12], bv[12], biasv[12];
    #pragma unroll
    for (int nt = 0; nt < 12; nt++) {
        int n = nt * 16 + q15;
        biasv[nt] = bias[n];
        gv[nt] = (n < DIM) ? g2[n] : 0.f;
        bv[nt] = (n < DIM) ? b2[n] : 0.f;
    }
    int mb = m0 + wave * 16 + quad * 4;
    #pragma unroll
    for (int r = 0; r < 4; r++) {
        int m = mb + r;
        float v[12];
        float s = 0.f, ss = 0.f;
        #pragma unroll
        for (int nt = 0; nt < 12; nt++) {
            int n = nt * 16 + q15;
            float x = acc[nt][r] + biasv[nt];
            if (n < DIM) x += resid[(size_t)m * DIM + n];
            else x = 0.f;
            v[nt] = x;
            s += x;
            ss += x * x;
        }
        #pragma unroll
        for (int o = 8; o > 0; o >>= 1) {
            s += __shfl_xor(s, o);
            ss += __shfl_xor(ss, o);
        }
        float mu = s * (1.f / DIM);
        float var = ss * (1.f / DIM) - mu * mu;
        float rstd = rsqrtf(var + 1e-5f);
        #pragma unroll
        for (int nt = 0; nt < 12; nt++) {
            int n = nt * 16 + q15;
            if (n < DIM) outf[(size_t)m * DIM + n] = v[nt];
            outb[(size_t)m * KP1 + n] = f2bf(gv[nt] * (v[nt] - mu) * rstd + bv[nt]);
        }
    }
}

// ---------------- MFMA attention v10: CHUNK=64 (9 chunks, half the barriers /
// loadKV address calcs, MFMA clusters of 8). Keys stored naturally per chunk in
// two 32-key groups; kf tile kt reads row (kt>>1)*32 + pr + (kt&1)*4 so the
// global tile index kc=ch*4+kt reproduces the bias table's key permutation
// unchanged. All 512 threads stage both K (2 dwords) and V (2 dwords)/chunk.
#define CHUNK 64
#define NCHUNK (NK / CHUNK)   // 9

__global__ __launch_bounds__(512) void attn_kernel(
        const __hip_bfloat16* __restrict__ qkvb,
        const ushort* __restrict__ biasC, __hip_bfloat16* __restrict__ aout) {
    __shared__ __align__(16) short Ks[2][CHUNK][32];     // 8 KB
    __shared__ __align__(16) short Vt[2][2][32][40];     // 10 KB (2 key-groups)

    int tid = threadIdx.x;
    int lane = tid & 63;
    int wave = tid >> 6;          // 0..7
    int q15 = lane & 15;
    int quad = lane >> 4;
    // swizzle: bid = 48*(win/8) + 8*head + (win%8)  ->  bid%8 == win%8 for all heads
    int bid = blockIdx.x;
    int grp = bid / 48;
    int r48 = bid - grp * 48;
    int head = r48 >> 3;
    int win = grp * 8 + (r48 & 7);
    int bh = win >> 4, bw = win & 15;

    const uint32_t* kvd = (const uint32_t*)qkvb;   // row = 288 dwords

    // Q fragments straight to registers (K zeroed at k=30,31 annihilates tail garbage)
    s8v qf[2];
    #pragma unroll
    for (int qt = 0; qt < 2; qt++) {
        int q = wave * 32 + qt * 16 + q15;
        int qy = q >> 4, qx = q & 15;
        size_t pos = (size_t)(bh * WS + qy) * WW + (bw * WS + qx);
        const uint32_t* qp = kvd + pos * 288 + head * 15 + quad * 4;
        uint32_t w0 = qp[0], w1 = qp[1], w2 = qp[2], w3 = qp[3];
        union { uint32_t u[4]; s8v v; } cv;
        cv.u[0] = w0; cv.u[1] = w1; cv.u[2] = w2; cv.u[3] = w3;
        qf[qt] = cv.v;
    }
    // zero aout pad cols 180..191 (proj A needs zeros)
    if (head == 0 && tid < 256) {
        int qy = tid >> 4, qx = tid & 15;
        size_t pos = (size_t)(bh * WS + qy) * WW + (bw * WS + qx);
        uint2 z = make_uint2(0u, 0u);
        uint2* oz = (uint2*)(aout + pos * KP1 + DIM);
        oz[0] = z; oz[1] = z; oz[2] = z;
    }

    // staging maps (every thread does both):
    // K: keyK = tid>>3 in [0,64), pK = tid&7 -> 2 dwords at pK*2
    // V: keyV = tid&63, pp = tid>>6 in [0,8) -> 2 dwords = dims pp*4..+3
    int keyK = tid >> 3, pK = tid & 7;
    int keyV = tid & 63, pp = tid >> 6;
    int gV = keyV >> 5, kv32 = keyV & 31;
    int pKs = pK ^ (((keyK >> 3) & 3) << 1);   // swizzled half-slot for K write

    auto rowbase = [&](int jk) -> const uint32_t* {
        int oy = jk / OWS, ox = jk - oy * OWS;
        int y = bh * WS - 4 + oy, x = bw * WS - 4 + ox;
        if ((unsigned)y < HH && (unsigned)x < WW)
            return kvd + ((size_t)y * WW + x) * 288;
        return nullptr;
    };
    auto loadKV = [&](int c0, uint32_t& ka, uint32_t& kb, uint32_t& va, uint32_t& vb) {
        ka = kb = va = vb = 0u;
        const uint32_t* rk = rowbase(c0 + keyK);
        if (rk) {
            const uint32_t* kp = rk + 90 + head * 15 + pK * 2;
            ka = kp[0];
            if (pK < 7) kb = kp[1];
        }
        const uint32_t* rv = rowbase(c0 + keyV);
        if (rv) {
            const uint32_t* vp = rv + 180 + head * 15 + pp * 2;
            va = vp[0];
            if (pp < 7) vb = vp[1];
        }
    };
    auto writeKV = [&](int bufi, uint32_t ka, uint32_t kb, uint32_t va, uint32_t vb) {
        *(uint2*)&Ks[bufi][keyK][pKs * 4] = make_uint2(ka, kb);  // pK==7: kb=0 -> dims 30,31 zero
        int d0 = pp * 4;
        Vt[bufi][gV][d0][kv32]     = (short)(va & 0xffff);
        Vt[bufi][gV][d0 + 1][kv32] = (short)(va >> 16);
        if (pp < 7) {
            Vt[bufi][gV][d0 + 2][kv32] = (short)(vb & 0xffff);
            Vt[bufi][gV][d0 + 3][kv32] = (short)(vb >> 16);
        } else {
            Vt[bufi][gV][30][kv32] = (short)0x3F80;   // ones row -> softmax denom
            Vt[bufi][gV][31][kv32] = 0;
        }
    };

    // bf16 bias prefetch: bb[kt][qt] (kt = global-tile within chunk, 0..3)
    const char* bBase = (const char*)biasC +
        ((size_t)head * (36 * 256 * 16) + (size_t)(wave * 32 + q15) * 16 + quad * 4) * 2;
    uint2 bb[4][2];
    auto loadBias = [&](int ch) {
        #pragma unroll
        for (int kt = 0; kt < 4; kt++)
            #pragma unroll
            for (int qt = 0; qt < 2; qt++)
                bb[kt][qt] = *(const uint2*)(bBase + (size_t)(ch * 4 + kt) * 8192 + qt * 512);
    };

    uint32_t kaA, kbA, vaA, vbA;
    uint32_t kaB, kbB, vaB, vbB;

    // prologue: A <- chunk0, B <- chunk1 (in flight), bias chunk0, LDS0 <- A
    loadKV(0,     kaA, kbA, vaA, vbA);
    loadKV(CHUNK, kaB, kbB, vaB, vbB);
    loadBias(0);
    writeKV(0, kaA, kbA, vaA, vbA);
    __syncthreads();

    f4v oacc[2][2];
    #pragma unroll
    for (int a = 0; a < 2; a++)
        #pragma unroll
        for (int b = 0; b < 2; b++) oacc[a][b] = (f4v){0.f, 0.f, 0.f, 0.f};

    int pr = ((q15 & 12) << 1) | (q15 & 3);   // permuted K-row base within a 32-group
    int rslot = (quad ^ (q15 >> 2)) * 8;      // swizzled 16B slot for kf reads

    auto body = [&](int ch, int bufR,
                    uint32_t& kaR, uint32_t& kbR, uint32_t& vaR, uint32_t& vbR,
                    uint32_t& kaW, uint32_t& kbW, uint32_t& vaW, uint32_t& vbW) {
        // kf[kt]: row (kt>>1)*32 + pr + (kt&1)*4 ; row>>3&3 == q15>>2 for all kt
        s8v kf[4];
        #pragma unroll
        for (int kt = 0; kt < 4; kt++)
            kf[kt] = *(const s8v*)&Ks[bufR][(kt >> 1) * 32 + pr + (kt & 1) * 4][rslot];
        s8v va[2][2];
        #pragma unroll
        for (int g = 0; g < 2; g++) {
            va[0][g] = *(const s8v*)&Vt[bufR][g][q15][quad * 8];
            va[1][g] = *(const s8v*)&Vt[bufR][g][16 + q15][quad * 8];
        }

        // QK phase: 8 MFMAs, C = 0
        f4v zf = (f4v){0.f, 0.f, 0.f, 0.f};
        f4v s[2][4];
        #pragma unroll
        for (int qt = 0; qt < 2; qt++)
            #pragma unroll
            for (int kt = 0; kt < 4; kt++)
                s[qt][kt] = __builtin_amdgcn_mfma_f32_16x16x32_bf16(kf[kt], qf[qt], zf, 0, 0, 0);

        // reload K/V two chunks ahead (issue early, wait lands next iter)
        if (ch + 2 < NCHUNK) loadKV((ch + 2) * CHUNK, kaR, kbR, vaR, vbR);

        // exp2(qk + bias) + pack: pbv[qt][g] holds keys {g*32+8*quad..+7}, col q
        s8v pbv[2][2];
        #pragma unroll
        for (int qt = 0; qt < 2; qt++)
            #pragma unroll
            for (int g = 0; g < 2; g++) {
                f4v c0 = s[qt][g * 2], c1 = s[qt][g * 2 + 1];
                uint2 b0 = bb[g * 2][qt], b1 = bb[g * 2 + 1][qt];
                union { uint32_t u[4]; s8v v; } pk;
                pk.u[0] = pack_bf2(__builtin_amdgcn_exp2f(c0[0] + bflo(b0.x)),
                                   __builtin_amdgcn_exp2f(c0[1] + bfhi(b0.x)));
                pk.u[1] = pack_bf2(__builtin_amdgcn_exp2f(c0[2] + bflo(b0.y)),
                                   __builtin_amdgcn_exp2f(c0[3] + bfhi(b0.y)));
                pk.u[2] = pack_bf2(__builtin_amdgcn_exp2f(c1[0] + bflo(b1.x)),
                                   __builtin_amdgcn_exp2f(c1[1] + bfhi(b1.x)));
                pk.u[3] = pack_bf2(__builtin_amdgcn_exp2f(c1[2] + bflo(b1.y)),
                                   __builtin_amdgcn_exp2f(c1[3] + bfhi(b1.y)));
                pbv[qt][g] = pk.v;
            }
        // bias prefetch for next chunk
        if (ch + 1 < NCHUNK) loadBias(ch + 1);

        // PV phase: 8 MFMAs (sum over both key groups)
        #pragma unroll
        for (int qt = 0; qt < 2; qt++)
            #pragma unroll
            for (int dt = 0; dt < 2; dt++) {
                oacc[dt][qt] = __builtin_amdgcn_mfma_f32_16x16x32_bf16(va[dt][0], pbv[qt][0], oacc[dt][qt], 0, 0, 0);
                oacc[dt][qt] = __builtin_amdgcn_mfma_f32_16x16x32_bf16(va[dt][1], pbv[qt][1], oacc[dt][qt], 0, 0, 0);
            }

        // write next chunk to the other LDS buffer (counted vmcnt wait, issued 1 iter ago)
        if (ch + 1 < NCHUNK) writeKV(bufR ^ 1, kaW, kbW, vaW, vbW);

        // counted-wait barrier: publish ds_writes only; global loads stay in flight
        asm volatile("s_waitcnt lgkmcnt(0)" ::: "memory");
        __builtin_amdgcn_sched_barrier(0);
        __builtin_amdgcn_s_barrier();
    };

    // 9 chunks: 4 pairs + 1 tail (A holds even chunks, B odd)
    #pragma unroll 1
    for (int t = 0; t < 4; t++) {
        body(2 * t,     0, kaA, kbA, vaA, vbA, kaB, kbB, vaB, vbB);
        body(2 * t + 1, 1, kaB, kbB, vaB, vbB, kaA, kbA, vaA, vbA);
    }
    body(8, 0, kaA, kbA, vaA, vbA, kaB, kbB, vaB, vbB);

    #pragma unroll
    for (int qt = 0; qt < 2; qt++) {
        float l = __shfl(oacc[1][qt][2], 48 | q15);   // dim 30 = ones row
        float rl = 1.0f / l;
        int q = wave * 32 + qt * 16 + q15;
        int qy = q >> 4, qx = q & 15;
        size_t pos = (size_t)(bh * WS + qy) * WW + (bw * WS + qx);
        uint32_t* od = (uint32_t*)(aout + pos * KP1 + head * HD);
        int dh = quad * 2;
        f4v o0 = oacc[0][qt], o1 = oacc[1][qt];
        od[dh]     = pack_bf2(o0[0] * rl, o0[1] * rl);
        od[dh + 1] = pack_bf2(o0[2] * rl, o0[3] * rl);
        od[8 + dh] = pack_bf2(o1[0] * rl, o1[1] * rl);
        if (quad < 3)
            od[8 + dh + 1] = pack_bf2(o1[2] * rl, o1[3] * rl);
    }
}

extern "C" void kernel_launch(void* const* d_in, const int* in_sizes, int n_in,
                              void* d_out, int out_size, void* d_ws, size_t ws_size,
                              hipStream_t stream) {
    const float* x      = (const float*)d_in[0];
    const int*   rpi    = (const int*)d_in[1];
    const float* n1g    = (const float*)d_in[4];
    const float* n1b    = (const float*)d_in[5];
    const float* q_w    = (const float*)d_in[6];
    const float* q_b    = (const float*)d_in[7];
    const float* kv_w   = (const float*)d_in[8];
    const float* kv_b   = (const float*)d_in[9];
    const float* rpb    = (const float*)d_in[10];
    const float* proj_w = (const float*)d_in[11];
    const float* proj_b = (const float*)d_in[12];
    const float* n2g    = (const float*)d_in[13];
    const float* n2b    = (const float*)d_in[14];
    const float* w1     = (const float*)d_in[15];
    const float* b1     = (const float*)d_in[16];
    const float* w2     = (const float*)d_in[17];
    const float* b2     = (const float*)d_in[18];
    float* out = (float*)d_out;

    char* ws = (char*)d_ws;
    short* qkvb  = (short*)(ws);                       // 75,497,472 B
    short* xn    = (short*)(ws + 75497472ull);         // 25,165,824 B
    ushort* biasC = (ushort*)(ws + 100663296ull);      //  1,769,472 B (bf16)
    short* wt    = (short*)(ws + 104202240ull);        //    589,824 B
    short* wt_qkv  = wt;                               // [576][192]
    short* wt_proj = wt + 110592;                      // [192][192]
    short* wt_1    = wt + 147456;                      // [384][192]
    short* wt_2    = wt + 221184;                      // [192][384]
    float* bvec  = (float*)(ws + 104202240ull + 589824ull);
    float* b_qkv  = bvec;
    float* b_proj = bvec + 576;
    float* b_1    = bvec + 768;
    float* b_2    = bvec + 1152;
    short* ao  = xn;                  // xn dead after qkv GEMM
    short* xn2 = qkvb;                // qkvb dead after attention
    short* h1  = qkvb + 12582912;     // +25,165,824 B, within qkvb region

    bias_kernel<<<884736 / 256, 256, 0, stream>>>(rpi, rpb, biasC);
    wconv_kernel<<<294912 / 256, 256, 0, stream>>>(q_w, kv_w, proj_w, w1, w2, wt);
    bconv_kernel<<<6, 256, 0, stream>>>(q_b, kv_b, proj_b, b1, b2, bvec);
    ln_kernel<<<L / 4, 256, 0, stream>>>(x, n1g, n1b, (__hip_bfloat16*)xn);
    mgemm<<<dim3(NQKV / 64, L / 128), 256, 0, stream>>>(
        xn, wt_qkv, b_qkv, nullptr, qkvb, KP1, NQKV, KP1 / 32, 0);
    attn_kernel<<<NWIN * HEADS, 512, 0, stream>>>(
        (const __hip_bfloat16*)qkvb, biasC, (__hip_bfloat16*)ao);
    projln<<<L / 64, 256, 0, stream>>>(
        ao, wt_proj, b_proj, x, n2g, n2b, out, xn2);
    mgemm<<<dim3(KP2 / 64, L / 128), 256, 0, stream>>>(
        xn2, wt_1, b_1, nullptr, h1, KP1, KP2, KP1 / 32, 1);
    mgemm<<<dim3(KP1 / 64, L / 128), 256, 0, stream>>>(
        h1, wt_2, b_2, out, nullptr, KP2, 0, KP2 / 32, 3);
}

// Round 9
// 411.027 us; speedup vs baseline: 1.0041x; 1.0041x over previous
//
#include <hip/hip_runtime.h>
#include <hip/hip_bf16.h>
#include <stdint.h>

#define DIM 180
#define WS 16
#define OWS 24
#define HEADS 6
#define HD 30
#define MLP_HID 360
#define HH 256
#define WW 256
#define L (HH * WW)
#define NWIN 256
#define NQ 256
#define NK 576

#define KP1 192
#define KP2 384
#define NQKV 576

// 30^-0.5 * log2(e): attn logits computed in log2 domain -> raw v_exp_f32
#define QSCALE 0.2633988734672831f
#define LOG2E 1.4426950408889634f

typedef float f4v __attribute__((ext_vector_type(4)));
typedef short s8v __attribute__((ext_vector_type(8)));
typedef short s4v __attribute__((ext_vector_type(4)));

static __device__ __forceinline__ short f2bf(float x) {
    union { __hip_bfloat16 h; short s; } u;
    u.h = __float2bfloat16(x);
    return u.s;
}
static __device__ __forceinline__ uint32_t pack_bf2(float lo, float hi) {
    union { __hip_bfloat162 h; uint32_t u; } u;
    u.h.x = __float2bfloat16(lo);
    u.h.y = __float2bfloat16(hi);
    return u.u;
}
static __device__ __forceinline__ float bflo(uint32_t u) {
    union { uint32_t i; float f; } c; c.i = u << 16; return c.f;
}
static __device__ __forceinline__ float bfhi(uint32_t u) {
    union { uint32_t i; float f; } c; c.i = u & 0xffff0000u; return c.f;
}

typedef __attribute__((address_space(1))) const unsigned int ga_u32;
typedef __attribute__((address_space(3))) unsigned int la_u32;
static __device__ __forceinline__ void gld16(const void* g, void* l) {
    __builtin_amdgcn_global_load_lds((ga_u32*)g, (la_u32*)l, 16, 0, 0);
}

// ---------------- LayerNorm (LN1): 4 rows per 256-thread block (1 row/wave)
__global__ __launch_bounds__(256) void ln_kernel(const float* __restrict__ x,
                                                 const float* __restrict__ g,
                                                 const float* __restrict__ b,
                                                 __hip_bfloat16* __restrict__ out) {
    int row = blockIdx.x * 4 + (threadIdx.x >> 6);
    int t = threadIdx.x & 63;
    const float* xr = x + (size_t)row * DIM;
    float v0 = xr[t];
    float v1 = xr[t + 64];
    float v2 = (t < DIM - 128) ? xr[t + 128] : 0.f;
    float s = v0 + v1 + v2;
    #pragma unroll
    for (int o = 32; o > 0; o >>= 1) s += __shfl_down(s, o);
    s = __shfl(s, 0);
    float mu = s * (1.f / DIM);
    float d0 = v0 - mu, d1 = v1 - mu;
    float d2 = (t < DIM - 128) ? (v2 - mu) : 0.f;
    float vs = d0 * d0 + d1 * d1 + d2 * d2;
    #pragma unroll
    for (int o = 32; o > 0; o >>= 1) vs += __shfl_down(vs, o);
    vs = __shfl(vs, 0);
    float rstd = rsqrtf(vs * (1.f / DIM) + 1e-5f);
    __hip_bfloat16* orow = out + (size_t)row * KP1;
    orow[t]      = __float2bfloat16(g[t] * d0 * rstd + b[t]);
    orow[t + 64] = __float2bfloat16(g[t + 64] * d1 * rstd + b[t + 64]);
    if (t < DIM - 128)
        orow[t + 128] = __float2bfloat16(g[t + 128] * d2 * rstd + b[t + 128]);
    if (t < KP1 - DIM) orow[DIM + t] = __float2bfloat16(0.f);
}

// ---------------- Bias in C-fragment order, bf16, with in-chunk key permutation.
// D-row j of tile kc corresponds to actual key
//   k = (kc>>1)*32 + 8*(j>>2) + (kc&1)*4 + (j&3)
__global__ __launch_bounds__(256) void bias_kernel(const int* __restrict__ rpi,
                                                   const float* __restrict__ rpb,
                                                   ushort* __restrict__ biasC) {
    int idx = blockIdx.x * 256 + threadIdx.x;   // 6*36*256*16 = 884736
    int j = idx & 15;
    int q = (idx >> 4) & 255;
    int r = idx >> 12;
    int kc = r % 36;
    int head = r / 36;
    int k = (kc >> 1) * 32 + ((j >> 2) << 3) + ((kc & 1) << 2) + (j & 3);
    int t = rpi[q * NK + k];
    biasC[idx] = (ushort)f2bf(rpb[t * HEADS + head] * LOG2E);
}

// ---------------- Weight convert (q scaled by QSCALE which includes log2e)
__global__ __launch_bounds__(256) void wconv_kernel(
        const float* __restrict__ qw, const float* __restrict__ kvw,
        const float* __restrict__ pw, const float* __restrict__ w1,
        const float* __restrict__ w2, short* __restrict__ wt) {
    int idx = blockIdx.x * 256 + threadIdx.x;   // 0 .. 294911
    float v = 0.f;
    if (idx < 110592) {                          // qkv: [576][192]
        int n = idx / KP1, k = idx - n * KP1;
        if (k < DIM) {
            if (n < DIM) v = qw[k * DIM + n] * QSCALE;
            else if (n < 540) v = kvw[k * (2 * DIM) + (n - DIM)];
        }
    } else if (idx < 147456) {                   // proj: [192][192]
        int r = idx - 110592;
        int n = r / KP1, k = r - n * KP1;
        if (k < DIM && n < DIM) v = pw[k * DIM + n];
    } else if (idx < 221184) {                   // w1: [384][192]
        int r = idx - 147456;
        int n = r / KP1, k = r - n * KP1;
        if (k < DIM && n < MLP_HID) v = w1[k * MLP_HID + n];
    } else {                                     // w2: [192][384]
        int r = idx - 221184;
        int n = r / KP2, k = r - n * KP2;
        if (k < MLP_HID && n < DIM) v = w2[k * DIM + n];
    }
    wt[idx] = f2bf(v);
}

__global__ __launch_bounds__(256) void bconv_kernel(
        const float* __restrict__ qb, const float* __restrict__ kvb,
        const float* __restrict__ pb, const float* __restrict__ b1,
        const float* __restrict__ b2, float* __restrict__ bv) {
    int idx = blockIdx.x * 256 + threadIdx.x;
    if (idx >= 1344) return;
    float v = 0.f;
    if (idx < 576) {
        if (idx < DIM) v = qb[idx] * QSCALE;
        else if (idx < 540) v = kvb[idx - DIM];
    } else if (idx < 768) {
        int n = idx - 576; if (n < DIM) v = pb[n];
    } else if (idx < 1152) {
        int n = idx - 768; if (n < MLP_HID) v = b1[n];
    } else {
        int n = idx - 1152; if (n < DIM) v = b2[n];
    }
    bv[idx] = v;
}

// ---------------- MFMA GEMM, BM=128 x BN=192 (full-192 N-panels).
// A re-read = N/192 per GEMM (qkv 3x, w1 2x, w2 1x) vs 9/6/3 at BN=64.
// Per wave-chunk: 2 af + 12 wf ds_reads -> 24 MFMAs (3x old density).
// mode 0: outb bf16 = r ; mode 1: outb bf16 = gelu_tanh(r) ; mode 3: outf f32 += r
__global__ __launch_bounds__(256) void mgemm192(
        const short* __restrict__ A, const short* __restrict__ Wt,
        const float* __restrict__ bias,
        float* __restrict__ outf, short* __restrict__ outb,
        int lda, int ldo, int nK, int mode) {
    __shared__ short As[2][128 * 32];    // 16 KB
    __shared__ short Wsm[2][192 * 32];   // 24.5 KB
    int tid = threadIdx.x;
    int lane = tid & 63, wave = tid >> 6;
    int q15 = lane & 15, quad = lane >> 4;
    int n0 = blockIdx.x * 192;
    int m0 = blockIdx.y * 128;

    auto stage = [&](int buf, int k0) {
        int lr = lane >> 2, c = lane & 3;
        const short* Ab = A + (size_t)m0 * lda + k0;
        #pragma unroll
        for (int i = 0; i < 2; i++) {
            int r = i * 64 + wave * 16 + lr;
            gld16(Ab + (size_t)r * lda + ((c ^ (r & 3)) * 8),
                  &As[buf][(i * 64 + wave * 16) * 32]);
        }
        #pragma unroll
        for (int i = 0; i < 3; i++) {
            int r = i * 64 + wave * 16 + lr;
            gld16(Wt + (size_t)(n0 + r) * lda + k0 + ((c ^ (r & 3)) * 8),
                  &Wsm[buf][(i * 64 + wave * 16) * 32]);
        }
    };

    f4v acc[2][12];
    #pragma unroll
    for (int a = 0; a < 2; a++)
        #pragma unroll
        for (int b = 0; b < 12; b++) acc[a][b] = (f4v){0.f, 0.f, 0.f, 0.f};

    stage(0, 0);
    __syncthreads();
    for (int ch = 0; ch < nK; ch++) {
        int buf = ch & 1;
        if (ch + 1 < nK) stage(buf ^ 1, (ch + 1) * 32);
        s8v af[2];
        #pragma unroll
        for (int mt = 0; mt < 2; mt++) {
            int r = wave * 32 + mt * 16 + q15;
            af[mt] = *(const s8v*)&As[buf][r * 32 + ((quad ^ (r & 3)) * 8)];
        }
        #pragma unroll
        for (int nt = 0; nt < 12; nt++) {
            int r = nt * 16 + q15;
            s8v wf = *(const s8v*)&Wsm[buf][r * 32 + ((quad ^ (r & 3)) * 8)];
            acc[0][nt] = __builtin_amdgcn_mfma_f32_16x16x32_bf16(af[0], wf, acc[0][nt], 0, 0, 0);
            acc[1][nt] = __builtin_amdgcn_mfma_f32_16x16x32_bf16(af[1], wf, acc[1][nt], 0, 0, 0);
        }
        __syncthreads();
    }

    #pragma unroll
    for (int mt = 0; mt < 2; mt++) {
        int mb = m0 + wave * 32 + mt * 16 + quad * 4;
        #pragma unroll
        for (int nt = 0; nt < 12; nt++) {
            int n = n0 + nt * 16 + q15;
            float bv = bias[n];
            f4v a = acc[mt][nt];
            #pragma unroll
            for (int r = 0; r < 4; r++) {
                int m = mb + r;
                float v = a[r] + bv;
                if (mode == 0) {
                    outb[(size_t)m * ldo + n] = f2bf(v);
                } else if (mode == 1) {
                    // tanh-approx gelu (max err ~3e-4, under bf16 rounding)
                    float y = 0.7978845608028654f * (v + 0.044715f * v * v * v);
                    float e = __builtin_amdgcn_exp2f(y * 2.885390081777927f);
                    float th = 1.f - 2.f / (1.f + e);
                    outb[(size_t)m * ldo + n] = f2bf(0.5f * v * (1.f + th));
                } else {
                    if (n < DIM) outf[(size_t)m * DIM + n] += v;
                }
            }
        }
    }
}

// ---------------- proj + residual + LN2 fused. BM=64, full N=192 per block.
__global__ __launch_bounds__(256) void projln(
        const short* __restrict__ A, const short* __restrict__ Wt,
        const float* __restrict__ bias, const float* __restrict__ resid,
        const float* __restrict__ g2, const float* __restrict__ b2,
        float* __restrict__ outf, short* __restrict__ outb) {
    __shared__ short As[2][64 * 32];
    __shared__ short Wsm[2][192 * 32];
    int tid = threadIdx.x;
    int lane = tid & 63, wave = tid >> 6;
    int q15 = lane & 15, quad = lane >> 4;
    int m0 = blockIdx.x * 64;

    auto stage = [&](int buf, int k0) {
        int lr = lane >> 2, c = lane & 3;
        const short* Ab = A + (size_t)m0 * KP1 + k0;
        {
            int r = wave * 16 + lr;
            gld16(Ab + (size_t)r * KP1 + ((c ^ (r & 3)) * 8),
                  &As[buf][(wave * 16) * 32]);
        }
        #pragma unroll
        for (int i = 0; i < 3; i++) {
            int r = i * 64 + wave * 16 + lr;
            gld16(Wt + (size_t)r * KP1 + k0 + ((c ^ (r & 3)) * 8),
                  &Wsm[buf][(i * 64 + wave * 16) * 32]);
        }
    };

    f4v acc[12];
    #pragma unroll
    for (int b = 0; b < 12; b++) acc[b] = (f4v){0.f, 0.f, 0.f, 0.f};

    stage(0, 0);
    __syncthreads();
    for (int ch = 0; ch < KP1 / 32; ch++) {
        int buf = ch & 1;
        if (ch + 1 < KP1 / 32) stage(buf ^ 1, (ch + 1) * 32);
        int ra = wave * 16 + q15;
        s8v af = *(const s8v*)&As[buf][ra * 32 + ((quad ^ (ra & 3)) * 8)];
        #pragma unroll
        for (int nt = 0; nt < 12; nt++) {
            int r = nt * 16 + q15;
            s8v wf = *(const s8v*)&Wsm[buf][r * 32 + ((quad ^ (r & 3)) * 8)];
            acc[nt] = __builtin_amdgcn_mfma_f32_16x16x32_bf16(af, wf, acc[nt], 0, 0, 0);
        }
        __syncthreads();
    }

    float gv[12], bv[12], biasv[12];
    #pragma unroll
    for (int nt = 0; nt < 12; nt++) {
        int n = nt * 16 + q15;
        biasv[nt] = bias[n];
        gv[nt] = (n < DIM) ? g2[n] : 0.f;
        bv[nt] = (n < DIM) ? b2[n] : 0.f;
    }
    int mb = m0 + wave * 16 + quad * 4;
    #pragma unroll
    for (int r = 0; r < 4; r++) {
        int m = mb + r;
        float v[12];
        float s = 0.f, ss = 0.f;
        #pragma unroll
        for (int nt = 0; nt < 12; nt++) {
            int n = nt * 16 + q15;
            float x = acc[nt][r] + biasv[nt];
            if (n < DIM) x += resid[(size_t)m * DIM + n];
            else x = 0.f;
            v[nt] = x;
            s += x;
            ss += x * x;
        }
        #pragma unroll
        for (int o = 8; o > 0; o >>= 1) {
            s += __shfl_xor(s, o);
            ss += __shfl_xor(ss, o);
        }
        float mu = s * (1.f / DIM);
        float var = ss * (1.f / DIM) - mu * mu;
        float rstd = rsqrtf(var + 1e-5f);
        #pragma unroll
        for (int nt = 0; nt < 12; nt++) {
            int n = nt * 16 + q15;
            if (n < DIM) outf[(size_t)m * DIM + n] = v[nt];
            outb[(size_t)m * KP1 + n] = f2bf(gv[nt] * (v[nt] - mu) * rstd + bv[nt]);
        }
    }
}

// ---------------- MFMA attention v9 (reverted from v10): CHUNK=32, 8-wave blocks,
// shared staging (K by waves 0-3, V by waves 4-7), in-register P via permuted K
// rows, bf16 bias added in exp2 phase, Ks XOR-swizzle, counted-wait barrier,
// XCD-co-locating swizzle. Proven 98 µs / 39% occupancy.
#define CHUNK 32
#define NCHUNK (NK / CHUNK)   // 18

__global__ __launch_bounds__(512) void attn_kernel(
        const __hip_bfloat16* __restrict__ qkvb,
        const ushort* __restrict__ biasC, __hip_bfloat16* __restrict__ aout) {
    __shared__ __align__(16) short Ks[2][CHUNK][32];   // 4 KB
    __shared__ __align__(16) short Vt[2][32][40];      // 5 KB

    int tid = threadIdx.x;
    int lane = tid & 63;
    int wave = tid >> 6;          // 0..7
    int q15 = lane & 15;
    int quad = lane >> 4;
    // swizzle: bid = 48*(win/8) + 8*head + (win%8)  ->  bid%8 == win%8 for all heads
    int bid = blockIdx.x;
    int grp = bid / 48;
    int r48 = bid - grp * 48;
    int head = r48 >> 3;
    int win = grp * 8 + (r48 & 7);
    int bh = win >> 4, bw = win & 15;

    const uint32_t* kvd = (const uint32_t*)qkvb;   // row = 288 dwords

    // Q fragments straight to registers (K zeroed at k=30,31 annihilates tail garbage)
    s8v qf[2];
    #pragma unroll
    for (int qt = 0; qt < 2; qt++) {
        int q = wave * 32 + qt * 16 + q15;
        int qy = q >> 4, qx = q & 15;
        size_t pos = (size_t)(bh * WS + qy) * WW + (bw * WS + qx);
        const uint32_t* qp = kvd + pos * 288 + head * 15 + quad * 4;
        uint32_t w0 = qp[0], w1 = qp[1], w2 = qp[2], w3 = qp[3];
        union { uint32_t u[4]; s8v v; } cv;
        cv.u[0] = w0; cv.u[1] = w1; cv.u[2] = w2; cv.u[3] = w3;
        qf[qt] = cv.v;
    }
    // zero aout pad cols 180..191 (proj A needs zeros)
    if (head == 0 && tid < 256) {
        int qy = tid >> 4, qx = tid & 15;
        size_t pos = (size_t)(bh * WS + qy) * WW + (bw * WS + qx);
        uint2 z = make_uint2(0u, 0u);
        uint2* oz = (uint2*)(aout + pos * KP1 + DIM);
        oz[0] = z; oz[1] = z; oz[2] = z;
    }

    // staging split: low half (waves 0-3) stages K, high half (waves 4-7) stages V
    bool lowh = tid < 256;
    int t2 = lowh ? tid : tid - 256;
    int keyK = t2 >> 3, pK = t2 & 7;     // K: 32 keys x 8 lanes (2 dwords each)
    int keyV = t2 & 31, pp = t2 >> 5;    // V: 32 keys x 8 lanes (2 dwords each)
    int pKs = pK ^ (((keyK >> 3) & 3) << 1);   // swizzled half-slot for K write

    auto rowbase = [&](int jk) -> const uint32_t* {
        int oy = jk / OWS, ox = jk - oy * OWS;
        int y = bh * WS - 4 + oy, x = bw * WS - 4 + ox;
        if ((unsigned)y < HH && (unsigned)x < WW)
            return kvd + ((size_t)y * WW + x) * 288;
        return nullptr;
    };
    auto loadKV = [&](int c0, uint32_t& a, uint32_t& b) {
        a = b = 0u;
        if (lowh) {
            const uint32_t* rk = rowbase(c0 + keyK);
            if (rk) {
                const uint32_t* kp = rk + 90 + head * 15 + pK * 2;
                a = kp[0];
                if (pK < 7) b = kp[1];
            }
        } else {
            const uint32_t* rv = rowbase(c0 + keyV);
            if (rv) {
                const uint32_t* vp = rv + 180 + head * 15 + pp * 2;
                a = vp[0];
                if (pp < 7) b = vp[1];
            }
        }
    };
    auto writeKV = [&](int bufi, uint32_t a, uint32_t b) {
        if (lowh) {
            // swizzled dest; pK==7: b=0 -> dims 30,31 zero
            *(uint2*)&Ks[bufi][keyK][pKs * 4] = make_uint2(a, b);
        } else {
            int d0 = pp * 4;
            Vt[bufi][d0][keyV]     = (short)(a & 0xffff);
            Vt[bufi][d0 + 1][keyV] = (short)(a >> 16);
            if (pp < 7) {
                Vt[bufi][d0 + 2][keyV] = (short)(b & 0xffff);
                Vt[bufi][d0 + 3][keyV] = (short)(b >> 16);
            } else {
                Vt[bufi][30][keyV] = (short)0x3F80;   // ones row -> softmax denom
                Vt[bufi][31][keyV] = 0;
            }
        }
    };

    // bf16 bias prefetch registers: bb[kt][qt] = 4 bf16 (j = quad*4..+3)
    const char* bBase = (const char*)biasC +
        ((size_t)head * (36 * 256 * 16) + (size_t)(wave * 32 + q15) * 16 + quad * 4) * 2;
    uint2 bb[2][2];
    auto loadBias = [&](int ch) {
        #pragma unroll
        for (int kt = 0; kt < 2; kt++)
            #pragma unroll
            for (int qt = 0; qt < 2; qt++)
                bb[kt][qt] = *(const uint2*)(bBase + (size_t)(ch * 2 + kt) * 8192 + qt * 512);
    };

    uint32_t aA, bA, aB, bB2;

    // prologue: A <- chunk0, B <- chunk1 (in flight), bias chunk0, LDS0 <- A
    loadKV(0, aA, bA);
    loadKV(CHUNK, aB, bB2);
    loadBias(0);
    writeKV(0, aA, bA);
    __syncthreads();

    f4v oacc[2][2];
    #pragma unroll
    for (int a = 0; a < 2; a++)
        #pragma unroll
        for (int b = 0; b < 2; b++) oacc[a][b] = (f4v){0.f, 0.f, 0.f, 0.f};

    int pr = ((q15 & 12) << 1) | (q15 & 3);   // permuted K-row base (kt=0: pr, kt=1: pr+4)
    int rslot = (quad ^ (q15 >> 2)) * 8;      // swizzled 16B slot for kf reads

    auto body = [&](int ch, int bufR,
                    uint32_t& aR, uint32_t& bR, uint32_t& aW, uint32_t& bW) {
        s8v kf0 = *(const s8v*)&Ks[bufR][pr][rslot];
        s8v kf1 = *(const s8v*)&Ks[bufR][pr + 4][rslot];
        s8v va0 = *(const s8v*)&Vt[bufR][q15][quad * 8];
        s8v va1 = *(const s8v*)&Vt[bufR][16 + q15][quad * 8];

        // QK phase: 4 MFMAs, C = 0 (no load dependency)
        f4v zf = (f4v){0.f, 0.f, 0.f, 0.f};
        f4v s0[2], s1[2];
        #pragma unroll
        for (int qt = 0; qt < 2; qt++) {
            s0[qt] = __builtin_amdgcn_mfma_f32_16x16x32_bf16(kf0, qf[qt], zf, 0, 0, 0);
            s1[qt] = __builtin_amdgcn_mfma_f32_16x16x32_bf16(kf1, qf[qt], zf, 0, 0, 0);
        }
        // reload K/V two chunks ahead into set R (issue early, wait lands next iter)
        if (ch + 2 < NCHUNK) loadKV((ch + 2) * CHUNK, aR, bR);

        // exp2(qk + bias) + pack: lane holds P for keys {8*quad..+7}, col q — PV B-frag
        s8v pbv[2];
        #pragma unroll
        for (int qt = 0; qt < 2; qt++) {
            uint2 b0 = bb[0][qt], b1 = bb[1][qt];
            union { uint32_t u[4]; s8v v; } pk;
            pk.u[0] = pack_bf2(__builtin_amdgcn_exp2f(s0[qt][0] + bflo(b0.x)),
                               __builtin_amdgcn_exp2f(s0[qt][1] + bfhi(b0.x)));
            pk.u[1] = pack_bf2(__builtin_amdgcn_exp2f(s0[qt][2] + bflo(b0.y)),
                               __builtin_amdgcn_exp2f(s0[qt][3] + bfhi(b0.y)));
            pk.u[2] = pack_bf2(__builtin_amdgcn_exp2f(s1[qt][0] + bflo(b1.x)),
                               __builtin_amdgcn_exp2f(s1[qt][1] + bfhi(b1.x)));
            pk.u[3] = pack_bf2(__builtin_amdgcn_exp2f(s1[qt][2] + bflo(b1.y)),
                               __builtin_amdgcn_exp2f(s1[qt][3] + bfhi(b1.y)));
            pbv[qt] = pk.v;
        }
        // bias prefetch for next chunk (bb now dead; loads overlap PV + barrier)
        if (ch + 1 < NCHUNK) loadBias(ch + 1);

        // PV phase: 4 MFMAs
        #pragma unroll
        for (int qt = 0; qt < 2; qt++) {
            oacc[0][qt] = __builtin_amdgcn_mfma_f32_16x16x32_bf16(va0, pbv[qt], oacc[0][qt], 0, 0, 0);
            oacc[1][qt] = __builtin_amdgcn_mfma_f32_16x16x32_bf16(va1, pbv[qt], oacc[1][qt], 0, 0, 0);
        }

        // write next chunk to the other LDS buffer (counted vmcnt wait, issued 1 iter ago)
        if (ch + 1 < NCHUNK) writeKV(bufR ^ 1, aW, bW);

        // counted-wait barrier: publish ds_writes only; global loads stay in flight
        asm volatile("s_waitcnt lgkmcnt(0)" ::: "memory");
        __builtin_amdgcn_sched_barrier(0);
        __builtin_amdgcn_s_barrier();
    };

    #pragma unroll 1
    for (int t = 0; t < NCHUNK / 2; t++) {
        body(2 * t,     0, aA, bA, aB, bB2);
        body(2 * t + 1, 1, aB, bB2, aA, bA);
    }

    #pragma unroll
    for (int qt = 0; qt < 2; qt++) {
        float l = __shfl(oacc[1][qt][2], 48 | q15);   // dim 30 = ones row
        float rl = 1.0f / l;
        int q = wave * 32 + qt * 16 + q15;
        int qy = q >> 4, qx = q & 15;
        size_t pos = (size_t)(bh * WS + qy) * WW + (bw * WS + qx);
        uint32_t* od = (uint32_t*)(aout + pos * KP1 + head * HD);
        int dh = quad * 2;
        f4v o0 = oacc[0][qt], o1 = oacc[1][qt];
        od[dh]     = pack_bf2(o0[0] * rl, o0[1] * rl);
        od[dh + 1] = pack_bf2(o0[2] * rl, o0[3] * rl);
        od[8 + dh] = pack_bf2(o1[0] * rl, o1[1] * rl);
        if (quad < 3)
            od[8 + dh + 1] = pack_bf2(o1[2] * rl, o1[3] * rl);
    }
}

extern "C" void kernel_launch(void* const* d_in, const int* in_sizes, int n_in,
                              void* d_out, int out_size, void* d_ws, size_t ws_size,
                              hipStream_t stream) {
    const float* x      = (const float*)d_in[0];
    const int*   rpi    = (const int*)d_in[1];
    const float* n1g    = (const float*)d_in[4];
    const float* n1b    = (const float*)d_in[5];
    const float* q_w    = (const float*)d_in[6];
    const float* q_b    = (const float*)d_in[7];
    const float* kv_w   = (const float*)d_in[8];
    const float* kv_b   = (const float*)d_in[9];
    const float* rpb    = (const float*)d_in[10];
    const float* proj_w = (const float*)d_in[11];
    const float* proj_b = (const float*)d_in[12];
    const float* n2g    = (const float*)d_in[13];
    const float* n2b    = (const float*)d_in[14];
    const float* w1     = (const float*)d_in[15];
    const float* b1     = (const float*)d_in[16];
    const float* w2     = (const float*)d_in[17];
    const float* b2     = (const float*)d_in[18];
    float* out = (float*)d_out;

    char* ws = (char*)d_ws;
    short* qkvb  = (short*)(ws);                       // 75,497,472 B
    short* xn    = (short*)(ws + 75497472ull);         // 25,165,824 B
    ushort* biasC = (ushort*)(ws + 100663296ull);      //  1,769,472 B (bf16)
    short* wt    = (short*)(ws + 104202240ull);        //    589,824 B
    short* wt_qkv  = wt;                               // [576][192]
    short* wt_proj = wt + 110592;                      // [192][192]
    short* wt_1    = wt + 147456;                      // [384][192]
    short* wt_2    = wt + 221184;                      // [192][384]
    float* bvec  = (float*)(ws + 104202240ull + 589824ull);
    float* b_qkv  = bvec;
    float* b_proj = bvec + 576;
    float* b_1    = bvec + 768;
    float* b_2    = bvec + 1152;
    short* ao  = xn;                  // xn dead after qkv GEMM
    short* xn2 = qkvb;                // qkvb dead after attention
    short* h1  = qkvb + 12582912;     // +25,165,824 B, within qkvb region

    bias_kernel<<<884736 / 256, 256, 0, stream>>>(rpi, rpb, biasC);
    wconv_kernel<<<294912 / 256, 256, 0, stream>>>(q_w, kv_w, proj_w, w1, w2, wt);
    bconv_kernel<<<6, 256, 0, stream>>>(q_b, kv_b, proj_b, b1, b2, bvec);
    ln_kernel<<<L / 4, 256, 0, stream>>>(x, n1g, n1b, (__hip_bfloat16*)xn);
    mgemm192<<<dim3(NQKV / 192, L / 128), 256, 0, stream>>>(
        xn, wt_qkv, b_qkv, nullptr, qkvb, KP1, NQKV, KP1 / 32, 0);
    attn_kernel<<<NWIN * HEADS, 512, 0, stream>>>(
        (const __hip_bfloat16*)qkvb, biasC, (__hip_bfloat16*)ao);
    projln<<<L / 64, 256, 0, stream>>>(
        ao, wt_proj, b_proj, x, n2g, n2b, out, xn2);
    mgemm192<<<dim3(KP2 / 192, L / 128), 256, 0, stream>>>(
        xn2, wt_1, b_1, nullptr, h1, KP1, KP2, KP1 / 32, 1);
    mgemm192<<<dim3(KP1 / 192, L / 128), 256, 0, stream>>>(
        h1, wt_2, b_2, out, nullptr, KP2, 0, KP2 / 32, 3);
}

// Round 11
// 359.827 us; speedup vs baseline: 1.1470x; 1.1423x over previous
//
#include <hip/hip_runtime.h>
#include <hip/hip_bf16.h>
#include <stdint.h>

#define DIM 180
#define WS 16
#define OWS 24
#define HEADS 6
#define HD 30
#define MLP_HID 360
#define HH 256
#define WW 256
#define L (HH * WW)
#define NWIN 256
#define NQ 256
#define NK 576

#define KP1 192
#define KP2 384
#define NQKV 576

// 30^-0.5 * log2(e): attn logits computed in log2 domain -> raw v_exp_f32
#define QSCALE 0.2633988734672831f
#define LOG2E 1.4426950408889634f

typedef float f4v __attribute__((ext_vector_type(4)));
typedef short s8v __attribute__((ext_vector_type(8)));
typedef short s4v __attribute__((ext_vector_type(4)));

static __device__ __forceinline__ short f2bf(float x) {
    union { __hip_bfloat16 h; short s; } u;
    u.h = __float2bfloat16(x);
    return u.s;
}
static __device__ __forceinline__ uint32_t pack_bf2(float lo, float hi) {
    union { __hip_bfloat162 h; uint32_t u; } u;
    u.h.x = __float2bfloat16(lo);
    u.h.y = __float2bfloat16(hi);
    return u.u;
}
static __device__ __forceinline__ float bflo(uint32_t u) {
    union { uint32_t i; float f; } c; c.i = u << 16; return c.f;
}
static __device__ __forceinline__ float bfhi(uint32_t u) {
    union { uint32_t i; float f; } c; c.i = u & 0xffff0000u; return c.f;
}

typedef __attribute__((address_space(1))) const unsigned int ga_u32;
typedef __attribute__((address_space(3))) unsigned int la_u32;
static __device__ __forceinline__ void gld16(const void* g, void* l) {
    __builtin_amdgcn_global_load_lds((ga_u32*)g, (la_u32*)l, 16, 0, 0);
}

// ---------------- LayerNorm (LN1): 4 rows per 256-thread block (1 row/wave)
__global__ __launch_bounds__(256) void ln_kernel(const float* __restrict__ x,
                                                 const float* __restrict__ g,
                                                 const float* __restrict__ b,
                                                 __hip_bfloat16* __restrict__ out) {
    int row = blockIdx.x * 4 + (threadIdx.x >> 6);
    int t = threadIdx.x & 63;
    const float* xr = x + (size_t)row * DIM;
    float v0 = xr[t];
    float v1 = xr[t + 64];
    float v2 = (t < DIM - 128) ? xr[t + 128] : 0.f;
    float s = v0 + v1 + v2;
    #pragma unroll
    for (int o = 32; o > 0; o >>= 1) s += __shfl_down(s, o);
    s = __shfl(s, 0);
    float mu = s * (1.f / DIM);
    float d0 = v0 - mu, d1 = v1 - mu;
    float d2 = (t < DIM - 128) ? (v2 - mu) : 0.f;
    float vs = d0 * d0 + d1 * d1 + d2 * d2;
    #pragma unroll
    for (int o = 32; o > 0; o >>= 1) vs += __shfl_down(vs, o);
    vs = __shfl(vs, 0);
    float rstd = rsqrtf(vs * (1.f / DIM) + 1e-5f);
    __hip_bfloat16* orow = out + (size_t)row * KP1;
    orow[t]      = __float2bfloat16(g[t] * d0 * rstd + b[t]);
    orow[t + 64] = __float2bfloat16(g[t + 64] * d1 * rstd + b[t + 64]);
    if (t < DIM - 128)
        orow[t + 128] = __float2bfloat16(g[t + 128] * d2 * rstd + b[t + 128]);
    if (t < KP1 - DIM) orow[DIM + t] = __float2bfloat16(0.f);
}

// ---------------- Bias in C-fragment order, bf16, with in-chunk key permutation.
// D-row j of tile kc corresponds to actual key
//   k = (kc>>1)*32 + 8*(j>>2) + (kc&1)*4 + (j&3)
__global__ __launch_bounds__(256) void bias_kernel(const int* __restrict__ rpi,
                                                   const float* __restrict__ rpb,
                                                   ushort* __restrict__ biasC) {
    int idx = blockIdx.x * 256 + threadIdx.x;   // 6*36*256*16 = 884736
    int j = idx & 15;
    int q = (idx >> 4) & 255;
    int r = idx >> 12;
    int kc = r % 36;
    int head = r / 36;
    int k = (kc >> 1) * 32 + ((j >> 2) << 3) + ((kc & 1) << 2) + (j & 3);
    int t = rpi[q * NK + k];
    biasC[idx] = (ushort)f2bf(rpb[t * HEADS + head] * LOG2E);
}

// ---------------- Weight convert (q scaled by QSCALE which includes log2e)
__global__ __launch_bounds__(256) void wconv_kernel(
        const float* __restrict__ qw, const float* __restrict__ kvw,
        const float* __restrict__ pw, const float* __restrict__ w1,
        const float* __restrict__ w2, short* __restrict__ wt) {
    int idx = blockIdx.x * 256 + threadIdx.x;   // 0 .. 294911
    float v = 0.f;
    if (idx < 110592) {                          // qkv: [576][192]
        int n = idx / KP1, k = idx - n * KP1;
        if (k < DIM) {
            if (n < DIM) v = qw[k * DIM + n] * QSCALE;
            else if (n < 540) v = kvw[k * (2 * DIM) + (n - DIM)];
        }
    } else if (idx < 147456) {                   // proj: [192][192]
        int r = idx - 110592;
        int n = r / KP1, k = r - n * KP1;
        if (k < DIM && n < DIM) v = pw[k * DIM + n];
    } else if (idx < 221184) {                   // w1: [384][192]
        int r = idx - 147456;
        int n = r / KP1, k = r - n * KP1;
        if (k < DIM && n < MLP_HID) v = w1[k * MLP_HID + n];
    } else {                                     // w2: [192][384]
        int r = idx - 221184;
        int n = r / KP2, k = r - n * KP2;
        if (k < MLP_HID && n < DIM) v = w2[k * DIM + n];
    }
    wt[idx] = f2bf(v);
}

__global__ __launch_bounds__(256) void bconv_kernel(
        const float* __restrict__ qb, const float* __restrict__ kvb,
        const float* __restrict__ pb, const float* __restrict__ b1,
        const float* __restrict__ b2, float* __restrict__ bv) {
    int idx = blockIdx.x * 256 + threadIdx.x;
    if (idx >= 1344) return;
    float v = 0.f;
    if (idx < 576) {
        if (idx < DIM) v = qb[idx] * QSCALE;
        else if (idx < 540) v = kvb[idx - DIM];
    } else if (idx < 768) {
        int n = idx - 576; if (n < DIM) v = pb[n];
    } else if (idx < 1152) {
        int n = idx - 768; if (n < MLP_HID) v = b1[n];
    } else {
        int n = idx - 1152; if (n < DIM) v = b2[n];
    }
    bv[idx] = v;
}

// ---------------- MFMA GEMM, BM=128 x BN=64, BK=32 (24 KB LDS -> 6 blocks/CU).
// 1-D grid with XCD-co-locating decode: bid = (y&7) + 8*(x + nx*(y>>3)) so all
// nx n-tiles of one m-tile share bid%8 -> same XCD -> the 48 KB A-panel is
// fetched into one L2 instead of up to 8.
// mode 0: outb bf16 = r ; mode 1: outb bf16 = gelu_tanh(r) ; mode 3: outf f32 += r
__global__ __launch_bounds__(256) void mgemm(
        const short* __restrict__ A, const short* __restrict__ Wt,
        const float* __restrict__ bias,
        float* __restrict__ outf, short* __restrict__ outb,
        int lda, int ldo, int nK, int mode, int nx) {
    __shared__ short As[2][128 * 32];
    __shared__ short Wsm[2][64 * 32];
    int tid = threadIdx.x;
    int lane = tid & 63, wave = tid >> 6;
    int q15 = lane & 15, quad = lane >> 4;
    // XCD-co-locating decode (bijective: L/128 = 512 is divisible by 8)
    int bid = blockIdx.x;
    int yl = bid & 7;
    int h = bid >> 3;
    int xx = h % nx;
    int y = (h / nx) * 8 + yl;
    int n0 = xx * 64;
    int m0 = y * 128;

    auto stage = [&](int buf, int k0) {
        int lr = lane >> 2, c = lane & 3;
        const short* Ab = A + (size_t)m0 * lda + k0;
        #pragma unroll
        for (int i = 0; i < 2; i++) {
            int r = i * 64 + wave * 16 + lr;
            gld16(Ab + (size_t)r * lda + ((c ^ (r & 3)) * 8),
                  &As[buf][(i * 64 + wave * 16) * 32]);
        }
        const short* Wb = Wt + (size_t)n0 * lda + k0;
        {
            int r = wave * 16 + lr;
            gld16(Wb + (size_t)r * lda + ((c ^ (r & 3)) * 8),
                  &Wsm[buf][(wave * 16) * 32]);
        }
    };

    f4v acc[2][4];
    #pragma unroll
    for (int a = 0; a < 2; a++)
        #pragma unroll
        for (int b = 0; b < 4; b++) acc[a][b] = (f4v){0.f, 0.f, 0.f, 0.f};

    stage(0, 0);
    __syncthreads();
    for (int ch = 0; ch < nK; ch++) {
        int buf = ch & 1;
        if (ch + 1 < nK) stage(buf ^ 1, (ch + 1) * 32);
        s8v af[2], wf[4];
        #pragma unroll
        for (int mt = 0; mt < 2; mt++) {
            int r = wave * 32 + mt * 16 + q15;
            af[mt] = *(const s8v*)&As[buf][r * 32 + ((quad ^ (r & 3)) * 8)];
        }
        #pragma unroll
        for (int nt = 0; nt < 4; nt++) {
            int r = nt * 16 + q15;
            wf[nt] = *(const s8v*)&Wsm[buf][r * 32 + ((quad ^ (r & 3)) * 8)];
        }
        #pragma unroll
        for (int mt = 0; mt < 2; mt++)
            #pragma unroll
            for (int nt = 0; nt < 4; nt++)
                acc[mt][nt] = __builtin_amdgcn_mfma_f32_16x16x32_bf16(
                    af[mt], wf[nt], acc[mt][nt], 0, 0, 0);
        __syncthreads();
    }

    #pragma unroll
    for (int mt = 0; mt < 2; mt++) {
        int mb = m0 + wave * 32 + mt * 16 + quad * 4;
        #pragma unroll
        for (int nt = 0; nt < 4; nt++) {
            int n = n0 + nt * 16 + q15;
            float bv = bias[n];
            f4v a = acc[mt][nt];
            #pragma unroll
            for (int r = 0; r < 4; r++) {
                int m = mb + r;
                float v = a[r] + bv;
                if (mode == 0) {
                    outb[(size_t)m * ldo + n] = f2bf(v);
                } else if (mode == 1) {
                    // tanh-approx gelu (max err ~3e-4, under bf16 rounding)
                    float y2 = 0.7978845608028654f * (v + 0.044715f * v * v * v);
                    float e = __builtin_amdgcn_exp2f(y2 * 2.885390081777927f);
                    float th = 1.f - 2.f / (1.f + e);
                    outb[(size_t)m * ldo + n] = f2bf(0.5f * v * (1.f + th));
                } else {
                    if (n < DIM) outf[(size_t)m * DIM + n] += v;
                }
            }
        }
    }
}

// ---------------- proj + residual + LN2 fused. BM=64, full N=192 per block.
__global__ __launch_bounds__(256) void projln(
        const short* __restrict__ A, const short* __restrict__ Wt,
        const float* __restrict__ bias, const float* __restrict__ resid,
        const float* __restrict__ g2, const float* __restrict__ b2,
        float* __restrict__ outf, short* __restrict__ outb) {
    __shared__ short As[2][64 * 32];
    __shared__ short Wsm[2][192 * 32];
    int tid = threadIdx.x;
    int lane = tid & 63, wave = tid >> 6;
    int q15 = lane & 15, quad = lane >> 4;
    int m0 = blockIdx.x * 64;

    auto stage = [&](int buf, int k0) {
        int lr = lane >> 2, c = lane & 3;
        const short* Ab = A + (size_t)m0 * KP1 + k0;
        {
            int r = wave * 16 + lr;
            gld16(Ab + (size_t)r * KP1 + ((c ^ (r & 3)) * 8),
                  &As[buf][(wave * 16) * 32]);
        }
        #pragma unroll
        for (int i = 0; i < 3; i++) {
            int r = i * 64 + wave * 16 + lr;
            gld16(Wt + (size_t)r * KP1 + k0 + ((c ^ (r & 3)) * 8),
                  &Wsm[buf][(i * 64 + wave * 16) * 32]);
        }
    };

    f4v acc[12];
    #pragma unroll
    for (int b = 0; b < 12; b++) acc[b] = (f4v){0.f, 0.f, 0.f, 0.f};

    stage(0, 0);
    __syncthreads();
    for (int ch = 0; ch < KP1 / 32; ch++) {
        int buf = ch & 1;
        if (ch + 1 < KP1 / 32) stage(buf ^ 1, (ch + 1) * 32);
        int ra = wave * 16 + q15;
        s8v af = *(const s8v*)&As[buf][ra * 32 + ((quad ^ (ra & 3)) * 8)];
        #pragma unroll
        for (int nt = 0; nt < 12; nt++) {
            int r = nt * 16 + q15;
            s8v wf = *(const s8v*)&Wsm[buf][r * 32 + ((quad ^ (r & 3)) * 8)];
            acc[nt] = __builtin_amdgcn_mfma_f32_16x16x32_bf16(af, wf, acc[nt], 0, 0, 0);
        }
        __syncthreads();
    }

    float gv[12], bv[12], biasv[12];
    #pragma unroll
    for (int nt = 0; nt < 12; nt++) {
        int n = nt * 16 + q15;
        biasv[nt] = bias[n];
        gv[nt] = (n < DIM) ? g2[n] : 0.f;
        bv[nt] = (n < DIM) ? b2[n] : 0.f;
    }
    int mb = m0 + wave * 16 + quad * 4;
    #pragma unroll
    for (int r = 0; r < 4; r++) {
        int m = mb + r;
        float v[12];
        float s = 0.f, ss = 0.f;
        #pragma unroll
        for (int nt = 0; nt < 12; nt++) {
            int n = nt * 16 + q15;
            float x = acc[nt][r] + biasv[nt];
            if (n < DIM) x += resid[(size_t)m * DIM + n];
            else x = 0.f;
            v[nt] = x;
            s += x;
            ss += x * x;
        }
        #pragma unroll
        for (int o = 8; o > 0; o >>= 1) {
            s += __shfl_xor(s, o);
            ss += __shfl_xor(ss, o);
        }
        float mu = s * (1.f / DIM);
        float var = ss * (1.f / DIM) - mu * mu;
        float rstd = rsqrtf(var + 1e-5f);
        #pragma unroll
        for (int nt = 0; nt < 12; nt++) {
            int n = nt * 16 + q15;
            if (n < DIM) outf[(size_t)m * DIM + n] = v[nt];
            outb[(size_t)m * KP1 + n] = f2bf(gv[nt] * (v[nt] - mu) * rstd + bv[nt]);
        }
    }
}

// ---------------- MFMA attention v9: CHUNK=32, 8-wave blocks, shared staging
// (K by waves 0-3, V by waves 4-7), in-register P via permuted K rows, bf16 bias
// added in exp2 phase, Ks XOR-swizzle, counted-wait barrier, XCD swizzle.
// Proven 98 µs / 40% occupancy.
#define CHUNK 32
#define NCHUNK (NK / CHUNK)   // 18

__global__ __launch_bounds__(512) void attn_kernel(
        const __hip_bfloat16* __restrict__ qkvb,
        const ushort* __restrict__ biasC, __hip_bfloat16* __restrict__ aout) {
    __shared__ __align__(16) short Ks[2][CHUNK][32];   // 4 KB
    __shared__ __align__(16) short Vt[2][32][40];      // 5 KB

    int tid = threadIdx.x;
    int lane = tid & 63;
    int wave = tid >> 6;          // 0..7
    int q15 = lane & 15;
    int quad = lane >> 4;
    // swizzle: bid = 48*(win/8) + 8*head + (win%8)  ->  bid%8 == win%8 for all heads
    int bid = blockIdx.x;
    int grp = bid / 48;
    int r48 = bid - grp * 48;
    int head = r48 >> 3;
    int win = grp * 8 + (r48 & 7);
    int bh = win >> 4, bw = win & 15;

    const uint32_t* kvd = (const uint32_t*)qkvb;   // row = 288 dwords

    // Q fragments straight to registers (K zeroed at k=30,31 annihilates tail garbage)
    s8v qf[2];
    #pragma unroll
    for (int qt = 0; qt < 2; qt++) {
        int q = wave * 32 + qt * 16 + q15;
        int qy = q >> 4, qx = q & 15;
        size_t pos = (size_t)(bh * WS + qy) * WW + (bw * WS + qx);
        const uint32_t* qp = kvd + pos * 288 + head * 15 + quad * 4;
        uint32_t w0 = qp[0], w1 = qp[1], w2 = qp[2], w3 = qp[3];
        union { uint32_t u[4]; s8v v; } cv;
        cv.u[0] = w0; cv.u[1] = w1; cv.u[2] = w2; cv.u[3] = w3;
        qf[qt] = cv.v;
    }
    // zero aout pad cols 180..191 (proj A needs zeros)
    if (head == 0 && tid < 256) {
        int qy = tid >> 4, qx = tid & 15;
        size_t pos = (size_t)(bh * WS + qy) * WW + (bw * WS + qx);
        uint2 z = make_uint2(0u, 0u);
        uint2* oz = (uint2*)(aout + pos * KP1 + DIM);
        oz[0] = z; oz[1] = z; oz[2] = z;
    }

    // staging split: low half (waves 0-3) stages K, high half (waves 4-7) stages V
    bool lowh = tid < 256;
    int t2 = lowh ? tid : tid - 256;
    int keyK = t2 >> 3, pK = t2 & 7;     // K: 32 keys x 8 lanes (2 dwords each)
    int keyV = t2 & 31, pp = t2 >> 5;    // V: 32 keys x 8 lanes (2 dwords each)
    int pKs = pK ^ (((keyK >> 3) & 3) << 1);   // swizzled half-slot for K write

    auto rowbase = [&](int jk) -> const uint32_t* {
        int oy = jk / OWS, ox = jk - oy * OWS;
        int y = bh * WS - 4 + oy, x = bw * WS - 4 + ox;
        if ((unsigned)y < HH && (unsigned)x < WW)
            return kvd + ((size_t)y * WW + x) * 288;
        return nullptr;
    };
    auto loadKV = [&](int c0, uint32_t& a, uint32_t& b) {
        a = b = 0u;
        if (lowh) {
            const uint32_t* rk = rowbase(c0 + keyK);
            if (rk) {
                const uint32_t* kp = rk + 90 + head * 15 + pK * 2;
                a = kp[0];
                if (pK < 7) b = kp[1];
            }
        } else {
            const uint32_t* rv = rowbase(c0 + keyV);
            if (rv) {
                const uint32_t* vp = rv + 180 + head * 15 + pp * 2;
                a = vp[0];
                if (pp < 7) b = vp[1];
            }
        }
    };
    auto writeKV = [&](int bufi, uint32_t a, uint32_t b) {
        if (lowh) {
            // swizzled dest; pK==7: b=0 -> dims 30,31 zero
            *(uint2*)&Ks[bufi][keyK][pKs * 4] = make_uint2(a, b);
        } else {
            int d0 = pp * 4;
            Vt[bufi][d0][keyV]     = (short)(a & 0xffff);
            Vt[bufi][d0 + 1][keyV] = (short)(a >> 16);
            if (pp < 7) {
                Vt[bufi][d0 + 2][keyV] = (short)(b & 0xffff);
                Vt[bufi][d0 + 3][keyV] = (short)(b >> 16);
            } else {
                Vt[bufi][30][keyV] = (short)0x3F80;   // ones row -> softmax denom
                Vt[bufi][31][keyV] = 0;
            }
        }
    };

    // bf16 bias prefetch registers: bb[kt][qt] = 4 bf16 (j = quad*4..+3)
    const char* bBase = (const char*)biasC +
        ((size_t)head * (36 * 256 * 16) + (size_t)(wave * 32 + q15) * 16 + quad * 4) * 2;
    uint2 bb[2][2];
    auto loadBias = [&](int ch) {
        #pragma unroll
        for (int kt = 0; kt < 2; kt++)
            #pragma unroll
            for (int qt = 0; qt < 2; qt++)
                bb[kt][qt] = *(const uint2*)(bBase + (size_t)(ch * 2 + kt) * 8192 + qt * 512);
    };

    uint32_t aA, bA, aB, bB2;

    // prologue: A <- chunk0, B <- chunk1 (in flight), bias chunk0, LDS0 <- A
    loadKV(0, aA, bA);
    loadKV(CHUNK, aB, bB2);
    loadBias(0);
    writeKV(0, aA, bA);
    __syncthreads();

    f4v oacc[2][2];
    #pragma unroll
    for (int a = 0; a < 2; a++)
        #pragma unroll
        for (int b = 0; b < 2; b++) oacc[a][b] = (f4v){0.f, 0.f, 0.f, 0.f};

    int pr = ((q15 & 12) << 1) | (q15 & 3);   // permuted K-row base (kt=0: pr, kt=1: pr+4)
    int rslot = (quad ^ (q15 >> 2)) * 8;      // swizzled 16B slot for kf reads

    auto body = [&](int ch, int bufR,
                    uint32_t& aR, uint32_t& bR, uint32_t& aW, uint32_t& bW) {
        s8v kf0 = *(const s8v*)&Ks[bufR][pr][rslot];
        s8v kf1 = *(const s8v*)&Ks[bufR][pr + 4][rslot];
        s8v va0 = *(const s8v*)&Vt[bufR][q15][quad * 8];
        s8v va1 = *(const s8v*)&Vt[bufR][16 + q15][quad * 8];

        // QK phase: 4 MFMAs, C = 0 (no load dependency)
        f4v zf = (f4v){0.f, 0.f, 0.f, 0.f};
        f4v s0[2], s1[2];
        #pragma unroll
        for (int qt = 0; qt < 2; qt++) {
            s0[qt] = __builtin_amdgcn_mfma_f32_16x16x32_bf16(kf0, qf[qt], zf, 0, 0, 0);
            s1[qt] = __builtin_amdgcn_mfma_f32_16x16x32_bf16(kf1, qf[qt], zf, 0, 0, 0);
        }
        // reload K/V two chunks ahead into set R (issue early, wait lands next iter)
        if (ch + 2 < NCHUNK) loadKV((ch + 2) * CHUNK, aR, bR);

        // exp2(qk + bias) + pack: lane holds P for keys {8*quad..+7}, col q — PV B-frag
        s8v pbv[2];
        #pragma unroll
        for (int qt = 0; qt < 2; qt++) {
            uint2 b0 = bb[0][qt], b1 = bb[1][qt];
            union { uint32_t u[4]; s8v v; } pk;
            pk.u[0] = pack_bf2(__builtin_amdgcn_exp2f(s0[qt][0] + bflo(b0.x)),
                               __builtin_amdgcn_exp2f(s0[qt][1] + bfhi(b0.x)));
            pk.u[1] = pack_bf2(__builtin_amdgcn_exp2f(s0[qt][2] + bflo(b0.y)),
                               __builtin_amdgcn_exp2f(s0[qt][3] + bfhi(b0.y)));
            pk.u[2] = pack_bf2(__builtin_amdgcn_exp2f(s1[qt][0] + bflo(b1.x)),
                               __builtin_amdgcn_exp2f(s1[qt][1] + bfhi(b1.x)));
            pk.u[3] = pack_bf2(__builtin_amdgcn_exp2f(s1[qt][2] + bflo(b1.y)),
                               __builtin_amdgcn_exp2f(s1[qt][3] + bfhi(b1.y)));
            pbv[qt] = pk.v;
        }
        // bias prefetch for next chunk (bb now dead; loads overlap PV + barrier)
        if (ch + 1 < NCHUNK) loadBias(ch + 1);

        // PV phase: 4 MFMAs
        #pragma unroll
        for (int qt = 0; qt < 2; qt++) {
            oacc[0][qt] = __builtin_amdgcn_mfma_f32_16x16x32_bf16(va0, pbv[qt], oacc[0][qt], 0, 0, 0);
            oacc[1][qt] = __builtin_amdgcn_mfma_f32_16x16x32_bf16(va1, pbv[qt], oacc[1][qt], 0, 0, 0);
        }

        // write next chunk to the other LDS buffer (counted vmcnt wait, issued 1 iter ago)
        if (ch + 1 < NCHUNK) writeKV(bufR ^ 1, aW, bW);

        // counted-wait barrier: publish ds_writes only; global loads stay in flight
        asm volatile("s_waitcnt lgkmcnt(0)" ::: "memory");
        __builtin_amdgcn_sched_barrier(0);
        __builtin_amdgcn_s_barrier();
    };

    #pragma unroll 1
    for (int t = 0; t < NCHUNK / 2; t++) {
        body(2 * t,     0, aA, bA, aB, bB2);
        body(2 * t + 1, 1, aB, bB2, aA, bA);
    }

    #pragma unroll
    for (int qt = 0; qt < 2; qt++) {
        float l = __shfl(oacc[1][qt][2], 48 | q15);   // dim 30 = ones row
        float rl = 1.0f / l;
        int q = wave * 32 + qt * 16 + q15;
        int qy = q >> 4, qx = q & 15;
        size_t pos = (size_t)(bh * WS + qy) * WW + (bw * WS + qx);
        uint32_t* od = (uint32_t*)(aout + pos * KP1 + head * HD);
        int dh = quad * 2;
        f4v o0 = oacc[0][qt], o1 = oacc[1][qt];
        od[dh]     = pack_bf2(o0[0] * rl, o0[1] * rl);
        od[dh + 1] = pack_bf2(o0[2] * rl, o0[3] * rl);
        od[8 + dh] = pack_bf2(o1[0] * rl, o1[1] * rl);
        if (quad < 3)
            od[8 + dh + 1] = pack_bf2(o1[2] * rl, o1[3] * rl);
    }
}

extern "C" void kernel_launch(void* const* d_in, const int* in_sizes, int n_in,
                              void* d_out, int out_size, void* d_ws, size_t ws_size,
                              hipStream_t stream) {
    const float* x      = (const float*)d_in[0];
    const int*   rpi    = (const int*)d_in[1];
    const float* n1g    = (const float*)d_in[4];
    const float* n1b    = (const float*)d_in[5];
    const float* q_w    = (const float*)d_in[6];
    const float* q_b    = (const float*)d_in[7];
    const float* kv_w   = (const float*)d_in[8];
    const float* kv_b   = (const float*)d_in[9];
    const float* rpb    = (const float*)d_in[10];
    const float* proj_w = (const float*)d_in[11];
    const float* proj_b = (const float*)d_in[12];
    const float* n2g    = (const float*)d_in[13];
    const float* n2b    = (const float*)d_in[14];
    const float* w1     = (const float*)d_in[15];
    const float* b1     = (const float*)d_in[16];
    const float* w2     = (const float*)d_in[17];
    const float* b2     = (const float*)d_in[18];
    float* out = (float*)d_out;

    char* ws = (char*)d_ws;
    short* qkvb  = (short*)(ws);                       // 75,497,472 B
    short* xn    = (short*)(ws + 75497472ull);         // 25,165,824 B
    ushort* biasC = (ushort*)(ws + 100663296ull);      //  1,769,472 B (bf16)
    short* wt    = (short*)(ws + 104202240ull);        //    589,824 B
    short* wt_qkv  = wt;                               // [576][192]
    short* wt_proj = wt + 110592;                      // [192][192]
    short* wt_1    = wt + 147456;                      // [384][192]
    short* wt_2    = wt + 221184;                      // [192][384]
    float* bvec  = (float*)(ws + 104202240ull + 589824ull);
    float* b_qkv  = bvec;
    float* b_proj = bvec + 576;
    float* b_1    = bvec + 768;
    float* b_2    = bvec + 1152;
    short* ao  = xn;                  // xn dead after qkv GEMM
    short* xn2 = qkvb;                // qkvb dead after attention
    short* h1  = qkvb + 12582912;     // +25,165,824 B, within qkvb region

    bias_kernel<<<884736 / 256, 256, 0, stream>>>(rpi, rpb, biasC);
    wconv_kernel<<<294912 / 256, 256, 0, stream>>>(q_w, kv_w, proj_w, w1, w2, wt);
    bconv_kernel<<<6, 256, 0, stream>>>(q_b, kv_b, proj_b, b1, b2, bvec);
    ln_kernel<<<L / 4, 256, 0, stream>>>(x, n1g, n1b, (__hip_bfloat16*)xn);
    mgemm<<<(NQKV / 64) * (L / 128), 256, 0, stream>>>(
        xn, wt_qkv, b_qkv, nullptr, qkvb, KP1, NQKV, KP1 / 32, 0, NQKV / 64);
    attn_kernel<<<NWIN * HEADS, 512, 0, stream>>>(
        (const __hip_bfloat16*)qkvb, biasC, (__hip_bfloat16*)ao);
    projln<<<L / 64, 256, 0, stream>>>(
        ao, wt_proj, b_proj, x, n2g, n2b, out, xn2);
    mgemm<<<(KP2 / 64) * (L / 128), 256, 0, stream>>>(
        xn2, wt_1, b_1, nullptr, h1, KP1, KP2, KP1 / 32, 1, KP2 / 64);
    mgemm<<<(KP1 / 64) * (L / 128), 256, 0, stream>>>(
        h1, wt_2, b_2, out, nullptr, KP2, 0, KP2 / 32, 3, KP1 / 64);
}

// Round 13
// 355.747 us; speedup vs baseline: 1.1602x; 1.0115x over previous
//
#include <hip/hip_runtime.h>
#include <hip/hip_bf16.h>
#include <stdint.h>

#define DIM 180
#define WS 16
#define OWS 24
#define HEADS 6
#define HD 30
#define MLP_HID 360
#define HH 256
#define WW 256
#define L (HH * WW)
#define NWIN 256
#define NQ 256
#define NK 576

#define KP1 192
#define KP2 384
#define NQKV 576

// 30^-0.5 * log2(e): attn logits computed in log2 domain -> raw v_exp_f32
#define QSCALE 0.2633988734672831f
#define LOG2E 1.4426950408889634f

typedef float f4v __attribute__((ext_vector_type(4)));
typedef short s8v __attribute__((ext_vector_type(8)));
typedef short s4v __attribute__((ext_vector_type(4)));

static __device__ __forceinline__ short f2bf(float x) {
    union { __hip_bfloat16 h; short s; } u;
    u.h = __float2bfloat16(x);
    return u.s;
}
static __device__ __forceinline__ uint32_t pack_bf2(float lo, float hi) {
    union { __hip_bfloat162 h; uint32_t u; } u;
    u.h.x = __float2bfloat16(lo);
    u.h.y = __float2bfloat16(hi);
    return u.u;
}
static __device__ __forceinline__ float bflo(uint32_t u) {
    union { uint32_t i; float f; } c; c.i = u << 16; return c.f;
}
static __device__ __forceinline__ float bfhi(uint32_t u) {
    union { uint32_t i; float f; } c; c.i = u & 0xffff0000u; return c.f;
}

typedef __attribute__((address_space(1))) const unsigned int ga_u32;
typedef __attribute__((address_space(3))) unsigned int la_u32;
static __device__ __forceinline__ void gld16(const void* g, void* l) {
    __builtin_amdgcn_global_load_lds((ga_u32*)g, (la_u32*)l, 16, 0, 0);
}

// ---------------- LayerNorm (LN1): 4 rows per 256-thread block (1 row/wave)
__global__ __launch_bounds__(256) void ln_kernel(const float* __restrict__ x,
                                                 const float* __restrict__ g,
                                                 const float* __restrict__ b,
                                                 __hip_bfloat16* __restrict__ out) {
    int row = blockIdx.x * 4 + (threadIdx.x >> 6);
    int t = threadIdx.x & 63;
    const float* xr = x + (size_t)row * DIM;
    float v0 = xr[t];
    float v1 = xr[t + 64];
    float v2 = (t < DIM - 128) ? xr[t + 128] : 0.f;
    float s = v0 + v1 + v2;
    #pragma unroll
    for (int o = 32; o > 0; o >>= 1) s += __shfl_down(s, o);
    s = __shfl(s, 0);
    float mu = s * (1.f / DIM);
    float d0 = v0 - mu, d1 = v1 - mu;
    float d2 = (t < DIM - 128) ? (v2 - mu) : 0.f;
    float vs = d0 * d0 + d1 * d1 + d2 * d2;
    #pragma unroll
    for (int o = 32; o > 0; o >>= 1) vs += __shfl_down(vs, o);
    vs = __shfl(vs, 0);
    float rstd = rsqrtf(vs * (1.f / DIM) + 1e-5f);
    __hip_bfloat16* orow = out + (size_t)row * KP1;
    orow[t]      = __float2bfloat16(g[t] * d0 * rstd + b[t]);
    orow[t + 64] = __float2bfloat16(g[t + 64] * d1 * rstd + b[t + 64]);
    if (t < DIM - 128)
        orow[t + 128] = __float2bfloat16(g[t + 128] * d2 * rstd + b[t + 128]);
    if (t < KP1 - DIM) orow[DIM + t] = __float2bfloat16(0.f);
}

// ---------------- Bias in C-fragment order, bf16, with in-chunk key permutation.
// D-row j of tile kc corresponds to actual key
//   k = (kc>>1)*32 + 8*(j>>2) + (kc&1)*4 + (j&3)
__global__ __launch_bounds__(256) void bias_kernel(const int* __restrict__ rpi,
                                                   const float* __restrict__ rpb,
                                                   ushort* __restrict__ biasC) {
    int idx = blockIdx.x * 256 + threadIdx.x;   // 6*36*256*16 = 884736
    int j = idx & 15;
    int q = (idx >> 4) & 255;
    int r = idx >> 12;
    int kc = r % 36;
    int head = r / 36;
    int k = (kc >> 1) * 32 + ((j >> 2) << 3) + ((kc & 1) << 2) + (j & 3);
    int t = rpi[q * NK + k];
    biasC[idx] = (ushort)f2bf(rpb[t * HEADS + head] * LOG2E);
}

// ---------------- Weight convert (q scaled by QSCALE which includes log2e)
__global__ __launch_bounds__(256) void wconv_kernel(
        const float* __restrict__ qw, const float* __restrict__ kvw,
        const float* __restrict__ pw, const float* __restrict__ w1,
        const float* __restrict__ w2, short* __restrict__ wt) {
    int idx = blockIdx.x * 256 + threadIdx.x;   // 0 .. 294911
    float v = 0.f;
    if (idx < 110592) {                          // qkv: [576][192]
        int n = idx / KP1, k = idx - n * KP1;
        if (k < DIM) {
            if (n < DIM) v = qw[k * DIM + n] * QSCALE;
            else if (n < 540) v = kvw[k * (2 * DIM) + (n - DIM)];
        }
    } else if (idx < 147456) {                   // proj: [192][192]
        int r = idx - 110592;
        int n = r / KP1, k = r - n * KP1;
        if (k < DIM && n < DIM) v = pw[k * DIM + n];
    } else if (idx < 221184) {                   // w1: [384][192]
        int r = idx - 147456;
        int n = r / KP1, k = r - n * KP1;
        if (k < DIM && n < MLP_HID) v = w1[k * MLP_HID + n];
    } else {                                     // w2: [192][384]
        int r = idx - 221184;
        int n = r / KP2, k = r - n * KP2;
        if (k < MLP_HID && n < DIM) v = w2[k * DIM + n];
    }
    wt[idx] = f2bf(v);
}

__global__ __launch_bounds__(256) void bconv_kernel(
        const float* __restrict__ qb, const float* __restrict__ kvb,
        const float* __restrict__ pb, const float* __restrict__ b1,
        const float* __restrict__ b2, float* __restrict__ bv) {
    int idx = blockIdx.x * 256 + threadIdx.x;
    if (idx >= 1344) return;
    float v = 0.f;
    if (idx < 576) {
        if (idx < DIM) v = qb[idx] * QSCALE;
        else if (idx < 540) v = kvb[idx - DIM];
    } else if (idx < 768) {
        int n = idx - 576; if (n < DIM) v = pb[n];
    } else if (idx < 1152) {
        int n = idx - 768; if (n < MLP_HID) v = b1[n];
    } else {
        int n = idx - 1152; if (n < DIM) v = b2[n];
    }
    bv[idx] = v;
}

// ---------------- MFMA GEMM, BM=128 x BN=64, BK=32 (24 KB LDS -> 6 blocks/CU).
// 1-D grid with XCD-co-locating decode: bid = (y&7) + 8*(x + nx*(y>>3)) so all
// nx n-tiles of one m-tile share bid%8 -> same XCD -> the 48 KB A-panel is
// fetched into one L2 instead of up to 8. (round 10: ~-50 us across 3 GEMMs)
// mode 0: outb bf16 = r ; mode 1: outb bf16 = gelu_tanh(r) ; mode 3: outf f32 += r
__global__ __launch_bounds__(256) void mgemm(
        const short* __restrict__ A, const short* __restrict__ Wt,
        const float* __restrict__ bias,
        float* __restrict__ outf, short* __restrict__ outb,
        int lda, int ldo, int nK, int mode, int nx) {
    __shared__ short As[2][128 * 32];
    __shared__ short Wsm[2][64 * 32];
    int tid = threadIdx.x;
    int lane = tid & 63, wave = tid >> 6;
    int q15 = lane & 15, quad = lane >> 4;
    // XCD-co-locating decode (bijective: L/128 = 512 is divisible by 8)
    int bid = blockIdx.x;
    int yl = bid & 7;
    int h = bid >> 3;
    int xx = h % nx;
    int y = (h / nx) * 8 + yl;
    int n0 = xx * 64;
    int m0 = y * 128;

    auto stage = [&](int buf, int k0) {
        int lr = lane >> 2, c = lane & 3;
        const short* Ab = A + (size_t)m0 * lda + k0;
        #pragma unroll
        for (int i = 0; i < 2; i++) {
            int r = i * 64 + wave * 16 + lr;
            gld16(Ab + (size_t)r * lda + ((c ^ (r & 3)) * 8),
                  &As[buf][(i * 64 + wave * 16) * 32]);
        }
        const short* Wb = Wt + (size_t)n0 * lda + k0;
        {
            int r = wave * 16 + lr;
            gld16(Wb + (size_t)r * lda + ((c ^ (r & 3)) * 8),
                  &Wsm[buf][(wave * 16) * 32]);
        }
    };

    f4v acc[2][4];
    #pragma unroll
    for (int a = 0; a < 2; a++)
        #pragma unroll
        for (int b = 0; b < 4; b++) acc[a][b] = (f4v){0.f, 0.f, 0.f, 0.f};

    stage(0, 0);
    __syncthreads();
    for (int ch = 0; ch < nK; ch++) {
        int buf = ch & 1;
        if (ch + 1 < nK) stage(buf ^ 1, (ch + 1) * 32);
        s8v af[2], wf[4];
        #pragma unroll
        for (int mt = 0; mt < 2; mt++) {
            int r = wave * 32 + mt * 16 + q15;
            af[mt] = *(const s8v*)&As[buf][r * 32 + ((quad ^ (r & 3)) * 8)];
        }
        #pragma unroll
        for (int nt = 0; nt < 4; nt++) {
            int r = nt * 16 + q15;
            wf[nt] = *(const s8v*)&Wsm[buf][r * 32 + ((quad ^ (r & 3)) * 8)];
        }
        #pragma unroll
        for (int mt = 0; mt < 2; mt++)
            #pragma unroll
            for (int nt = 0; nt < 4; nt++)
                acc[mt][nt] = __builtin_amdgcn_mfma_f32_16x16x32_bf16(
                    af[mt], wf[nt], acc[mt][nt], 0, 0, 0);
        __syncthreads();
    }

    #pragma unroll
    for (int mt = 0; mt < 2; mt++) {
        int mb = m0 + wave * 32 + mt * 16 + quad * 4;
        #pragma unroll
        for (int nt = 0; nt < 4; nt++) {
            int n = n0 + nt * 16 + q15;
            float bv = bias[n];
            f4v a = acc[mt][nt];
            #pragma unroll
            for (int r = 0; r < 4; r++) {
                int m = mb + r;
                float v = a[r] + bv;
                if (mode == 0) {
                    outb[(size_t)m * ldo + n] = f2bf(v);
                } else if (mode == 1) {
                    // tanh-approx gelu (max err ~3e-4, under bf16 rounding)
                    float y2 = 0.7978845608028654f * (v + 0.044715f * v * v * v);
                    float e = __builtin_amdgcn_exp2f(y2 * 2.885390081777927f);
                    float th = 1.f - 2.f / (1.f + e);
                    outb[(size_t)m * ldo + n] = f2bf(0.5f * v * (1.f + th));
                } else {
                    if (n < DIM) outf[(size_t)m * DIM + n] += v;
                }
            }
        }
    }
}

// ---------------- proj + residual + LN2 fused. BM=64, full N=192 per block.
__global__ __launch_bounds__(256) void projln(
        const short* __restrict__ A, const short* __restrict__ Wt,
        const float* __restrict__ bias, const float* __restrict__ resid,
        const float* __restrict__ g2, const float* __restrict__ b2,
        float* __restrict__ outf, short* __restrict__ outb) {
    __shared__ short As[2][64 * 32];
    __shared__ short Wsm[2][192 * 32];
    int tid = threadIdx.x;
    int lane = tid & 63, wave = tid >> 6;
    int q15 = lane & 15, quad = lane >> 4;
    int m0 = blockIdx.x * 64;

    auto stage = [&](int buf, int k0) {
        int lr = lane >> 2, c = lane & 3;
        const short* Ab = A + (size_t)m0 * KP1 + k0;
        {
            int r = wave * 16 + lr;
            gld16(Ab + (size_t)r * KP1 + ((c ^ (r & 3)) * 8),
                  &As[buf][(wave * 16) * 32]);
        }
        #pragma unroll
        for (int i = 0; i < 3; i++) {
            int r = i * 64 + wave * 16 + lr;
            gld16(Wt + (size_t)r * KP1 + k0 + ((c ^ (r & 3)) * 8),
                  &Wsm[buf][(i * 64 + wave * 16) * 32]);
        }
    };

    f4v acc[12];
    #pragma unroll
    for (int b = 0; b < 12; b++) acc[b] = (f4v){0.f, 0.f, 0.f, 0.f};

    stage(0, 0);
    __syncthreads();
    for (int ch = 0; ch < KP1 / 32; ch++) {
        int buf = ch & 1;
        if (ch + 1 < KP1 / 32) stage(buf ^ 1, (ch + 1) * 32);
        int ra = wave * 16 + q15;
        s8v af = *(const s8v*)&As[buf][ra * 32 + ((quad ^ (ra & 3)) * 8)];
        #pragma unroll
        for (int nt = 0; nt < 12; nt++) {
            int r = nt * 16 + q15;
            s8v wf = *(const s8v*)&Wsm[buf][r * 32 + ((quad ^ (r & 3)) * 8)];
            acc[nt] = __builtin_amdgcn_mfma_f32_16x16x32_bf16(af, wf, acc[nt], 0, 0, 0);
        }
        __syncthreads();
    }

    float gv[12], bv[12], biasv[12];
    #pragma unroll
    for (int nt = 0; nt < 12; nt++) {
        int n = nt * 16 + q15;
        biasv[nt] = bias[n];
        gv[nt] = (n < DIM) ? g2[n] : 0.f;
        bv[nt] = (n < DIM) ? b2[n] : 0.f;
    }
    int mb = m0 + wave * 16 + quad * 4;
    #pragma unroll
    for (int r = 0; r < 4; r++) {
        int m = mb + r;
        float v[12];
        float s = 0.f, ss = 0.f;
        #pragma unroll
        for (int nt = 0; nt < 12; nt++) {
            int n = nt * 16 + q15;
            float x = acc[nt][r] + biasv[nt];
            if (n < DIM) x += resid[(size_t)m * DIM + n];
            else x = 0.f;
            v[nt] = x;
            s += x;
            ss += x * x;
        }
        #pragma unroll
        for (int o = 8; o > 0; o >>= 1) {
            s += __shfl_xor(s, o);
            ss += __shfl_xor(ss, o);
        }
        float mu = s * (1.f / DIM);
        float var = ss * (1.f / DIM) - mu * mu;
        float rstd = rsqrtf(var + 1e-5f);
        #pragma unroll
        for (int nt = 0; nt < 12; nt++) {
            int n = nt * 16 + q15;
            if (n < DIM) outf[(size_t)m * DIM + n] = v[nt];
            outb[(size_t)m * KP1 + n] = f2bf(gv[nt] * (v[nt] - mu) * rstd + bv[nt]);
        }
    }
}

// ---------------- MFMA attention v11: v9 + incremental K/V row addressing.
// The per-chunk key index advances by exactly 32 (chunks are loaded in order),
// so the jk/24 division + full 2-D rebuild per loadKV is replaced by a per-thread
// (oy,ox) state advanced with 3-4 VALU (32 = 24+8: oy+=1, ox+=8, wrap at 24),
// with the head/lane offset and tail predicate hoisted out of the loop.
// Attacks the measured-dominant pipe (VALUBusy 52%).
#define CHUNK 32
#define NCHUNK (NK / CHUNK)   // 18

__global__ __launch_bounds__(512) void attn_kernel(
        const __hip_bfloat16* __restrict__ qkvb,
        const ushort* __restrict__ biasC, __hip_bfloat16* __restrict__ aout) {
    __shared__ __align__(16) short Ks[2][CHUNK][32];   // 4 KB
    __shared__ __align__(16) short Vt[2][32][40];      // 5 KB

    int tid = threadIdx.x;
    int lane = tid & 63;
    int wave = tid >> 6;          // 0..7
    int q15 = lane & 15;
    int quad = lane >> 4;
    // swizzle: bid = 48*(win/8) + 8*head + (win%8)  ->  bid%8 == win%8 for all heads
    int bid = blockIdx.x;
    int grp = bid / 48;
    int r48 = bid - grp * 48;
    int head = r48 >> 3;
    int win = grp * 8 + (r48 & 7);
    int bh = win >> 4, bw = win & 15;

    const uint32_t* kvd = (const uint32_t*)qkvb;   // row = 288 dwords

    // Q fragments straight to registers (K zeroed at k=30,31 annihilates tail garbage)
    s8v qf[2];
    #pragma unroll
    for (int qt = 0; qt < 2; qt++) {
        int q = wave * 32 + qt * 16 + q15;
        int qy = q >> 4, qx = q & 15;
        size_t pos = (size_t)(bh * WS + qy) * WW + (bw * WS + qx);
        const uint32_t* qp = kvd + pos * 288 + head * 15 + quad * 4;
        uint32_t w0 = qp[0], w1 = qp[1], w2 = qp[2], w3 = qp[3];
        union { uint32_t u[4]; s8v v; } cv;
        cv.u[0] = w0; cv.u[1] = w1; cv.u[2] = w2; cv.u[3] = w3;
        qf[qt] = cv.v;
    }
    // zero aout pad cols 180..191 (proj A needs zeros)
    if (head == 0 && tid < 256) {
        int qy = tid >> 4, qx = tid & 15;
        size_t pos = (size_t)(bh * WS + qy) * WW + (bw * WS + qx);
        uint2 z = make_uint2(0u, 0u);
        uint2* oz = (uint2*)(aout + pos * KP1 + DIM);
        oz[0] = z; oz[1] = z; oz[2] = z;
    }

    // staging split: low half (waves 0-3) stages K, high half (waves 4-7) stages V
    bool lowh = tid < 256;
    int t2 = lowh ? tid : tid - 256;
    int keyK = t2 >> 3, pK = t2 & 7;     // K: 32 keys x 8 lanes (2 dwords each)
    int keyV = t2 & 31, pp = t2 >> 5;    // V: 32 keys x 8 lanes (2 dwords each)
    int pKs = pK ^ (((keyK >> 3) & 3) << 1);   // swizzled half-slot for K write

    // incremental row-index state: this thread's key index within the 576-key
    // window walk is myKey + 32*chunk; 32 = 24+8 so each chunk: oy+=1, ox+=8 (wrap)
    int myKey = lowh ? keyK : keyV;            // [0,32)
    int oy = (myKey >= OWS) ? 1 : 0;
    int ox = myKey - oy * OWS;
    int lofs = lowh ? (90 + head * 15 + pK * 2) : (180 + head * 15 + pp * 2);
    bool tail = lowh ? (pK < 7) : (pp < 7);

    auto loadKV = [&](uint32_t& a, uint32_t& b) {
        a = b = 0u;
        int y = bh * WS - 4 + oy, x = bw * WS - 4 + ox;
        if ((unsigned)y < HH && (unsigned)x < WW) {
            const uint32_t* p = kvd + ((size_t)y * WW + x) * 288 + lofs;
            a = p[0];
            if (tail) b = p[1];
        }
        // advance to next chunk's row (key += 32 = 24 + 8)
        ox += 8; oy += 1;
        if (ox >= OWS) { ox -= OWS; oy += 1; }
    };
    auto writeKV = [&](int bufi, uint32_t a, uint32_t b) {
        if (lowh) {
            // swizzled dest; pK==7: b=0 -> dims 30,31 zero
            *(uint2*)&Ks[bufi][keyK][pKs * 4] = make_uint2(a, b);
        } else {
            int d0 = pp * 4;
            Vt[bufi][d0][keyV]     = (short)(a & 0xffff);
            Vt[bufi][d0 + 1][keyV] = (short)(a >> 16);
            if (pp < 7) {
                Vt[bufi][d0 + 2][keyV] = (short)(b & 0xffff);
                Vt[bufi][d0 + 3][keyV] = (short)(b >> 16);
            } else {
                Vt[bufi][30][keyV] = (short)0x3F80;   // ones row -> softmax denom
                Vt[bufi][31][keyV] = 0;
            }
        }
    };

    // bf16 bias prefetch registers: bb[kt][qt] = 4 bf16 (j = quad*4..+3)
    const char* bBase = (const char*)biasC +
        ((size_t)head * (36 * 256 * 16) + (size_t)(wave * 32 + q15) * 16 + quad * 4) * 2;
    uint2 bb[2][2];
    auto loadBias = [&](int ch) {
        #pragma unroll
        for (int kt = 0; kt < 2; kt++)
            #pragma unroll
            for (int qt = 0; qt < 2; qt++)
                bb[kt][qt] = *(const uint2*)(bBase + (size_t)(ch * 2 + kt) * 8192 + qt * 512);
    };

    uint32_t aA, bA, aB, bB2;

    // prologue: A <- chunk0, B <- chunk1 (in flight), bias chunk0, LDS0 <- A
    loadKV(aA, bA);
    loadKV(aB, bB2);
    loadBias(0);
    writeKV(0, aA, bA);
    __syncthreads();

    f4v oacc[2][2];
    #pragma unroll
    for (int a = 0; a < 2; a++)
        #pragma unroll
        for (int b = 0; b < 2; b++) oacc[a][b] = (f4v){0.f, 0.f, 0.f, 0.f};

    int pr = ((q15 & 12) << 1) | (q15 & 3);   // permuted K-row base (kt=0: pr, kt=1: pr+4)
    int rslot = (quad ^ (q15 >> 2)) * 8;      // swizzled 16B slot for kf reads

    auto body = [&](int ch, int bufR,
                    uint32_t& aR, uint32_t& bR, uint32_t& aW, uint32_t& bW) {
        s8v kf0 = *(const s8v*)&Ks[bufR][pr][rslot];
        s8v kf1 = *(const s8v*)&Ks[bufR][pr + 4][rslot];
        s8v va0 = *(const s8v*)&Vt[bufR][q15][quad * 8];
        s8v va1 = *(const s8v*)&Vt[bufR][16 + q15][quad * 8];

        // QK phase: 4 MFMAs, C = 0 (no load dependency)
        f4v zf = (f4v){0.f, 0.f, 0.f, 0.f};
        f4v s0[2], s1[2];
        #pragma unroll
        for (int qt = 0; qt < 2; qt++) {
            s0[qt] = __builtin_amdgcn_mfma_f32_16x16x32_bf16(kf0, qf[qt], zf, 0, 0, 0);
            s1[qt] = __builtin_amdgcn_mfma_f32_16x16x32_bf16(kf1, qf[qt], zf, 0, 0, 0);
        }
        // reload K/V two chunks ahead into set R (issue early, wait lands next iter)
        if (ch + 2 < NCHUNK) loadKV(aR, bR);

        // exp2(qk + bias) + pack: lane holds P for keys {8*quad..+7}, col q — PV B-frag
        s8v pbv[2];
        #pragma unroll
        for (int qt = 0; qt < 2; qt++) {
            uint2 b0 = bb[0][qt], b1 = bb[1][qt];
            union { uint32_t u[4]; s8v v; } pk;
            pk.u[0] = pack_bf2(__builtin_amdgcn_exp2f(s0[qt][0] + bflo(b0.x)),
                               __builtin_amdgcn_exp2f(s0[qt][1] + bfhi(b0.x)));
            pk.u[1] = pack_bf2(__builtin_amdgcn_exp2f(s0[qt][2] + bflo(b0.y)),
                               __builtin_amdgcn_exp2f(s0[qt][3] + bfhi(b0.y)));
            pk.u[2] = pack_bf2(__builtin_amdgcn_exp2f(s1[qt][0] + bflo(b1.x)),
                               __builtin_amdgcn_exp2f(s1[qt][1] + bfhi(b1.x)));
            pk.u[3] = pack_bf2(__builtin_amdgcn_exp2f(s1[qt][2] + bflo(b1.y)),
                               __builtin_amdgcn_exp2f(s1[qt][3] + bfhi(b1.y)));
            pbv[qt] = pk.v;
        }
        // bias prefetch for next chunk (bb now dead; loads overlap PV + barrier)
        if (ch + 1 < NCHUNK) loadBias(ch + 1);

        // PV phase: 4 MFMAs
        #pragma unroll
        for (int qt = 0; qt < 2; qt++) {
            oacc[0][qt] = __builtin_amdgcn_mfma_f32_16x16x32_bf16(va0, pbv[qt], oacc[0][qt], 0, 0, 0);
            oacc[1][qt] = __builtin_amdgcn_mfma_f32_16x16x32_bf16(va1, pbv[qt], oacc[1][qt], 0, 0, 0);
        }

        // write next chunk to the other LDS buffer (counted vmcnt wait, issued 1 iter ago)
        if (ch + 1 < NCHUNK) writeKV(bufR ^ 1, aW, bW);

        // counted-wait barrier: publish ds_writes only; global loads stay in flight
        asm volatile("s_waitcnt lgkmcnt(0)" ::: "memory");
        __builtin_amdgcn_sched_barrier(0);
        __builtin_amdgcn_s_barrier();
    };

    #pragma unroll 1
    for (int t = 0; t < NCHUNK / 2; t++) {
        body(2 * t,     0, aA, bA, aB, bB2);
        body(2 * t + 1, 1, aB, bB2, aA, bA);
    }

    #pragma unroll
    for (int qt = 0; qt < 2; qt++) {
        float l = __shfl(oacc[1][qt][2], 48 | q15);   // dim 30 = ones row
        float rl = 1.0f / l;
        int q = wave * 32 + qt * 16 + q15;
        int qy = q >> 4, qx = q & 15;
        size_t pos = (size_t)(bh * WS + qy) * WW + (bw * WS + qx);
        uint32_t* od = (uint32_t*)(aout + pos * KP1 + head * HD);
        int dh = quad * 2;
        f4v o0 = oacc[0][qt], o1 = oacc[1][qt];
        od[dh]     = pack_bf2(o0[0] * rl, o0[1] * rl);
        od[dh + 1] = pack_bf2(o0[2] * rl, o0[3] * rl);
        od[8 + dh] = pack_bf2(o1[0] * rl, o1[1] * rl);
        if (quad < 3)
            od[8 + dh + 1] = pack_bf2(o1[2] * rl, o1[3] * rl);
    }
}

extern "C" void kernel_launch(void* const* d_in, const int* in_sizes, int n_in,
                              void* d_out, int out_size, void* d_ws, size_t ws_size,
                              hipStream_t stream) {
    const float* x      = (const float*)d_in[0];
    const int*   rpi    = (const int*)d_in[1];
    const float* n1g    = (const float*)d_in[4];
    const float* n1b    = (const float*)d_in[5];
    const float* q_w    = (const float*)d_in[6];
    const float* q_b    = (const float*)d_in[7];
    const float* kv_w   = (const float*)d_in[8];
    const float* kv_b   = (const float*)d_in[9];
    const float* rpb    = (const float*)d_in[10];
    const float* proj_w = (const float*)d_in[11];
    const float* proj_b = (const float*)d_in[12];
    const float* n2g    = (const float*)d_in[13];
    const float* n2b    = (const float*)d_in[14];
    const float* w1     = (const float*)d_in[15];
    const float* b1     = (const float*)d_in[16];
    const float* w2     = (const float*)d_in[17];
    const float* b2     = (const float*)d_in[18];
    float* out = (float*)d_out;

    char* ws = (char*)d_ws;
    short* qkvb  = (short*)(ws);                       // 75,497,472 B
    short* xn    = (short*)(ws + 75497472ull);         // 25,165,824 B
    ushort* biasC = (ushort*)(ws + 100663296ull);      //  1,769,472 B (bf16)
    short* wt    = (short*)(ws + 104202240ull);        //    589,824 B
    short* wt_qkv  = wt;                               // [576][192]
    short* wt_proj = wt + 110592;                      // [192][192]
    short* wt_1    = wt + 147456;                      // [384][192]
    short* wt_2    = wt + 221184;                      // [192][384]
    float* bvec  = (float*)(ws + 104202240ull + 589824ull);
    float* b_qkv  = bvec;
    float* b_proj = bvec + 576;
    float* b_1    = bvec + 768;
    float* b_2    = bvec + 1152;
    short* ao  = xn;                  // xn dead after qkv GEMM
    short* xn2 = qkvb;                // qkvb dead after attention
    short* h1  = qkvb + 12582912;     // +25,165,824 B, within qkvb region

    bias_kernel<<<884736 / 256, 256, 0, stream>>>(rpi, rpb, biasC);
    wconv_kernel<<<294912 / 256, 256, 0, stream>>>(q_w, kv_w, proj_w, w1, w2, wt);
    bconv_kernel<<<6, 256, 0, stream>>>(q_b, kv_b, proj_b, b1, b2, bvec);
    ln_kernel<<<L / 4, 256, 0, stream>>>(x, n1g, n1b, (__hip_bfloat16*)xn);
    mgemm<<<(NQKV / 64) * (L / 128), 256, 0, stream>>>(
        xn, wt_qkv, b_qkv, nullptr, qkvb, KP1, NQKV, KP1 / 32, 0, NQKV / 64);
    attn_kernel<<<NWIN * HEADS, 512, 0, stream>>>(
        (const __hip_bfloat16*)qkvb, biasC, (__hip_bfloat16*)ao);
    projln<<<L / 64, 256, 0, stream>>>(
        ao, wt_proj, b_proj, x, n2g, n2b, out, xn2);
    mgemm<<<(KP2 / 64) * (L / 128), 256, 0, stream>>>(
        xn2, wt_1, b_1, nullptr, h1, KP1, KP2, KP1 / 32, 1, KP2 / 64);
    mgemm<<<(KP1 / 64) * (L / 128), 256, 0, stream>>>(
        h1, wt_2, b_2, out, nullptr, KP2, 0, KP2 / 32, 3, KP1 / 64);
}